// Round 7
// baseline (514.598 us; speedup 1.0000x reference)
//
#include <hip/hip_runtime.h>
#include <type_traits>

// Problem constants (ExaoneFlashAttention): B=4, S=1024, T=4096, D_MODEL=2048,
// H=32, KVH=8, HD=64, GROUPS=4, SCALE=1/8. All bf16 MFMA, f32 accum.
// Attention scale * log2(e) folded into Wq transpose -> softmax in exp2 domain.
// Max-free softmax (logits bounded). RoPE applied by rope_vkt pre-pass (in-place
// on qkv; QK^T invariant under common d-relabeling, rope commutes with Q scale).

typedef __bf16 bf16x8 __attribute__((ext_vector_type(8)));
typedef __bf16 bf16x4 __attribute__((ext_vector_type(4)));
typedef float f32x4 __attribute__((ext_vector_type(4)));
typedef unsigned short u16;
typedef unsigned int u32;

#define DEVI __device__ __forceinline__

DEVI u16 f2bf(float f) {           // RNE f32->bf16 (finite inputs)
  u32 u = __builtin_bit_cast(u32, f);
  u += 0x7FFF + ((u >> 16) & 1);
  return (u16)(u >> 16);
}

// async global->LDS, 16B per lane. LDS dest must be wave-uniform base + lane*16.
DEVI void ld16_lds(const void* g, void* l) {
  __builtin_amdgcn_global_load_lds((const __attribute__((address_space(1))) u32*)g,
                                   (__attribute__((address_space(3))) u32*)l, 16, 0, 0);
}

template <int N> DEVI void waitvm() {   // counted vmcnt (T4) — compile-time immediate
  if constexpr (N == 0) asm volatile("s_waitcnt vmcnt(0)" ::: "memory");
  else if constexpr (N == 8) asm volatile("s_waitcnt vmcnt(8)" ::: "memory");
  else if constexpr (N == 10) asm volatile("s_waitcnt vmcnt(10)" ::: "memory");
  else static_assert(N == 0, "unsupported vmcnt");
}
DEVI void lgkm0() {                     // rule #18: sched_barrier after the wait
  asm volatile("s_waitcnt lgkmcnt(0)" ::: "memory");
  __builtin_amdgcn_sched_barrier(0);
}
DEVI void barrier() { __builtin_amdgcn_s_barrier(); }

// ---------------- fused prep: f32->bf16 convert + 4 weight transposes -------------------
__global__ __launch_bounds__(256) void prep(const float* __restrict__ hs, u16* __restrict__ hsB,
                                            const float* __restrict__ Wq, const float* __restrict__ Wk,
                                            const float* __restrict__ Wv, const float* __restrict__ Wo,
                                            u16* __restrict__ wqkvT, u16* __restrict__ woT,
                                            float qscale) {
  int b = blockIdx.x;
  if (b < 8192) {                      // ---- convert hs (4096x2048 f32) -> hsB bf16 ----
    int i = b * 256 + threadIdx.x;
    float4 v = ((const float4*)hs)[i];
    ushort4 o;
    o.x = f2bf(v.x); o.y = f2bf(v.y); o.z = f2bf(v.z); o.w = f2bf(v.w);
    ((ushort4*)hsB)[i] = o;
    return;
  }
  b -= 8192;
  const float* src; u16* dst; int R, C, bx, by; float sc = 1.0f;
  if (b < 4096)      { src = Wq; dst = wqkvT;                         R = 2048; C = 2048; bx = b & 63; by = b >> 6; sc = qscale; }
  else if (b < 5120) { b -= 4096; src = Wk; dst = wqkvT + (size_t)2048 * 2048; R = 2048; C = 512; bx = b & 15; by = b >> 4; }
  else if (b < 6144) { b -= 5120; src = Wv; dst = wqkvT + (size_t)2560 * 2048; R = 2048; C = 512; bx = b & 15; by = b >> 4; }
  else               { b -= 6144; src = Wo; dst = woT;                R = 2048; C = 2048; bx = b & 63; by = b >> 6; }
  __shared__ float tile[32][33];
  int c0 = bx * 32, r0 = by * 32;
  int tx = threadIdx.x & 31, ty = threadIdx.x >> 5;   // ty 0..7
#pragma unroll
  for (int i = 0; i < 32; i += 8)
    tile[ty + i][tx] = src[(size_t)(r0 + ty + i) * C + (c0 + tx)];
  __syncthreads();
#pragma unroll
  for (int i = 0; i < 32; i += 8)
    dst[(size_t)(c0 + ty + i) * R + (r0 + tx)] = f2bf(tile[tx][ty + i] * sc);
}

// ---------------- GEMM v7: read-hoisted single-barrier pipeline, 2 blocks/CU -----------
// C(MxN) = A(MxK) * BT(NxK)^T, bf16 in, f32 acc. BM=128 x BN (192 QKV / 128 Wo),
// BK=64, 256 thr = 4 waves (2M x 2N), wave tile 64 x BN/2 (n-cols = interleaved
// halves so each B half is a contiguous stageable range). LDS 80/64 KB -> 2 blk/CU.
// Round-6 lesson: per-phase {reads -> lgkm0 -> MFMA} serializes a wave's LDS and
// matrix pipes (measured MfmaUtil 39% = MFMA/(MFMA+LDS+sync)). v7 hoists all frag
// reads ONE K-TILE AHEAD so they complete under the current tile's MFMA run:
//   iter t: stage(t+2)->buf[t&1]          (10/8 DMA; full-iter cover >= HBM lat)
//           issue ldAF(t+1) -> af[nxt]    (8 ds_read, hidden under mm0)
//           mm0(t): af[cur] x b0          (24/16 MFMA, setprio)
//           issue ldB0(t+1) -> b0 (freed) (WAR: compiler keeps reads after mm0)
//           mm1(t): af[cur] x b1          (24/16 MFMA)
//           issue ldB1(t+1) -> b1 (freed)
//           waitvm<0> ; lgkm0 ; barrier   (single barrier per K-tile)
// Hazards: stage(t+2) overwrites tile t -- its reads lgkm0'd+barrier'd at t-1;
// reads(t+1) issue only after stage(t+1) drained (waitvm at t-1 end + barrier);
// iter-end lgkm0 forces b1(t+1) reads complete before buf[nxt] is restaged (t+1).
// Regs: af x2 (64) + b0 (24) + b1 (24) + acc (96) ~ 230 VGPR, fits 2 waves/SIMD
// (LDS already pins 2 blocks/CU, so no occupancy cost).
// T2 chunk swizzle unchanged (pre-swizzled global source, same XOR on read).
// T1 XCD swizzle: nwg=512 %8==0.
template <typename OutT, int BN>
__global__ __launch_bounds__(256, 2) void gemm3(const u16* __restrict__ A,
                                                const u16* __restrict__ BT,
                                                OutT* __restrict__ C, int M, int N, int K) {
  constexpr int NF = BN / 32;         // n-frags per wave: 6 (192) / 4 (128)
  constexpr int NH = NF / 2;          // frags per n-half: 3 / 2
  constexpr int HW = BN / 2;          // B half rows: 96 / 64
  constexpr int SW = HW / 2;          // per-wave span within a half: 48 / 32
  constexpr int LB0 = BN / 64;        // B-half stage loads/thr: 3 / 2
  constexpr int VMW = 4 + 2 * LB0;    // loads per full-tile stage: 10 / 8
  __shared__ u16 As[2][128 * 64];
  __shared__ u16 Bs[2][BN * 64];
  const int tid = threadIdx.x;
  const int lane = tid & 63, wave = tid >> 6;
  const int quad = lane >> 4, l16 = lane & 15;

  // ---- XCD-aware block swizzle (bijective: nwg = 512, %8 == 0) ----
  const int nwg = gridDim.x * gridDim.y;
  const int bid = blockIdx.y * gridDim.x + blockIdx.x;
  const int swz = (bid & 7) * (nwg >> 3) + (bid >> 3);
  const int m0 = (swz / gridDim.x) * 128, n0 = (swz % gridDim.x) * BN;
  const int wr = wave >> 1, wc = wave & 1;   // 2M x 2N wave grid

  f32x4 acc[4][NF] = {};

  // ---- stage one full K-tile t -> buf t&1 (A: 4 loads/thr, B: 2*LB0) ----
  auto stage = [&](int t) {
    const int buf = t & 1;
    {
      u16* D = &As[buf][0];
      const u16* G = A + (size_t)m0 * K + t * 64;
#pragma unroll
      for (int i = 0; i < 4; ++i) {
        int id = i * 256 + tid, row = id >> 3, ch = id & 7;
        ld16_lds(G + (size_t)row * K + (ch ^ (row & 7)) * 8, D + id * 8);
      }
    }
#pragma unroll
    for (int h = 0; h < 2; ++h) {
      u16* D = &Bs[buf][h * HW * 64];
      const u16* G = BT + (size_t)(n0 + h * HW) * K + t * 64;
#pragma unroll
      for (int i = 0; i < LB0; ++i) {
        int id = i * 256 + tid, row = id >> 3, ch = id & 7;
        // h*HW multiple of 8 -> (local row & 7) == (global row & 7)
        ld16_lds(G + (size_t)row * K + (ch ^ (row & 7)) * 8, D + id * 8);
      }
    }
  };

  // ---- register fragments: af ping-pong (2 sets), b0/b1 single ----
  bf16x8 af[2][4][2], b0[NH][2], b1[NH][2];
  auto ldAF = [&](int s, int buf) {
#pragma unroll
    for (int i = 0; i < 4; ++i)
#pragma unroll
      for (int ks = 0; ks < 2; ++ks) {
        int r = wr * 64 + i * 16 + l16;
        af[s][i][ks] = *(const bf16x8*)&As[buf][r * 64 + (((ks * 4 + quad) ^ (r & 7)) * 8)];
      }
  };
  auto ldB = [&](bf16x8 (&bv)[NH][2], int half, int buf) {
#pragma unroll
    for (int j = 0; j < NH; ++j)
#pragma unroll
      for (int ks = 0; ks < 2; ++ks) {
        int rb = half * HW + wc * SW + j * 16 + l16;
        bv[j][ks] = *(const bf16x8*)&Bs[buf][rb * 64 + (((ks * 4 + quad) ^ (rb & 7)) * 8)];
      }
  };
  auto mmh = [&](int s, bf16x8 (&bv)[NH][2], int jo) {   // 4 x NH x 2 MFMA (T5 wrap)
    __builtin_amdgcn_s_setprio(1);
#pragma unroll
    for (int i = 0; i < 4; ++i)
#pragma unroll
      for (int j = 0; j < NH; ++j)
#pragma unroll
        for (int ks = 0; ks < 2; ++ks)
          acc[i][jo + j] =
              __builtin_amdgcn_mfma_f32_16x16x32_bf16(af[s][i][ks], bv[j][ks], acc[i][jo + j], 0, 0, 0);
    __builtin_amdgcn_s_setprio(0);
  };

  const int NT = K / 64;   // 32 for both GEMMs

  // ---- prologue: stage tiles 0,1; publish tile0; read frags(0); publish reads ----
  stage(0); stage(1);
  waitvm<VMW>();            // drain stage(0); stage(1) keeps flying
  barrier();
  ldAF(0, 0); ldB(b0, 0, 0); ldB(b1, 1, 0);
  lgkm0();
  barrier();                // all waves' tile-0 reads done (stage(2) will overwrite)

#pragma unroll 2
  for (int t = 0; t < NT; ++t) {
    const int cur = t & 1, nxt = cur ^ 1;
    if (t + 2 < NT) stage(t + 2);            // -> buf[cur] (tile t dead)
    if (t + 1 < NT) ldAF(nxt, nxt);          // 8 reads, hidden under mm0
    mmh(cur, b0, 0);
    if (t + 1 < NT) ldB(b0, 0, nxt);         // 6/4 reads into freed b0, under mm1
    mmh(cur, b1, NH);
    if (t + 1 < NT) {
      ldB(b1, 1, nxt);                       // 6/4 reads into freed b1
      waitvm<0>();                           // stage(t+2) landed (full-iter cover);
                                             // stage(t+1) was drained last iter
      lgkm0();                               // all frag reads of t+1 complete
      barrier();                             // publish; next iter may restage buf[nxt]
    }
  }

  // ---- epilogue: C/D layout col=lane&15, row=quad*4+r ----
#pragma unroll
  for (int i = 0; i < 4; ++i) {
    int row = m0 + wr * 64 + i * 16 + quad * 4;
#pragma unroll
    for (int j = 0; j < NF; ++j) {
      int half = j / NH, jj = j % NH;
      int col = n0 + half * HW + wc * SW + jj * 16 + l16;
#pragma unroll
      for (int r = 0; r < 4; ++r) {
        size_t off = (size_t)(row + r) * N + col;
        if constexpr (sizeof(OutT) == 2) C[off] = f2bf(acc[i][j][r]);
        else C[off] = acc[i][j][r];
      }
    }
  }
}

// ---------------- rope_vkt: RoPE Q/K in-place + V tile images ---------------------------
// Grid (8 kt, 32 h, 4 b). Every block ropes the Q tile [128 tok x 64] of head h.
// Blocks with h<8 additionally rope the K tile of kvh=h and build the V image
// (transposed, chunk-swizzled, k-permuted). RoPE pair (d, d+32) is in-row ->
// one thread owns a full pair group; cs/sn indexed by global token.
__global__ __launch_bounds__(256) void rope_vkt(u16* __restrict__ qkv,
                                                u16* __restrict__ vkt,
                                                const float* __restrict__ cs,
                                                const float* __restrict__ sn) {
  const int kt = blockIdx.x, h = blockIdx.y, b = blockIdx.z;
  const int tid = threadIdx.x;
  const size_t tok0 = (size_t)b * 1024 + (size_t)kt * 128;

  // ---- RoPE: 2 threads per row, 2 pair-groups (8 pairs each) per thread ----
  {
    const int r = tid >> 1, hf = tid & 1;
    const size_t t = tok0 + r;
    const float* cr = cs + t * 32;
    const float* sr = sn + t * 32;
    u16* qrow = qkv + t * 3072 + h * 64;
    u16* krow = qkv + t * 3072 + 2048 + h * 64;   // used only when h<8
#pragma unroll
    for (int gg = 0; gg < 2; ++gg) {
      const int g = hf * 2 + gg;                  // pair-group 0..3 (d = g*8+e)
      float cv[8], sv[8];
#pragma unroll
      for (int e = 0; e < 8; ++e) { cv[e] = cr[g * 8 + e]; sv[e] = sr[g * 8 + e]; }
      {
        bf16x8 a = *(bf16x8*)&qrow[g * 8];
        bf16x8 b2 = *(bf16x8*)&qrow[g * 8 + 32];
#pragma unroll
        for (int e = 0; e < 8; ++e) {
          float x1 = (float)a[e], x2 = (float)b2[e];
          a[e] = (__bf16)(x1 * cv[e] - x2 * sv[e]);
          b2[e] = (__bf16)(x2 * cv[e] + x1 * sv[e]);
        }
        *(bf16x8*)&qrow[g * 8] = a;
        *(bf16x8*)&qrow[g * 8 + 32] = b2;
      }
      if (h < 8) {
        bf16x8 a = *(bf16x8*)&krow[g * 8];
        bf16x8 b2 = *(bf16x8*)&krow[g * 8 + 32];
#pragma unroll
        for (int e = 0; e < 8; ++e) {
          float x1 = (float)a[e], x2 = (float)b2[e];
          a[e] = (__bf16)(x1 * cv[e] - x2 * sv[e]);
          b2[e] = (__bf16)(x2 * cv[e] + x1 * sv[e]);
        }
        *(bf16x8*)&krow[g * 8] = a;
        *(bf16x8*)&krow[g * 8 + 32] = b2;
      }
    }
  }
  if (h >= 8) return;

  // ---- V image build (kvh = h) ----
  __shared__ u16 Vn[128 * 64];
  const u16* src = qkv + tok0 * 3072 + 2560 + h * 64;
  {
    int tok = tid >> 1, hf = tid & 1;
    const uint4* s4 = (const uint4*)(src + (size_t)tok * 3072 + hf * 32);
    uint4* d4 = (uint4*)&Vn[tok * 64 + hf * 32];
#pragma unroll
    for (int j = 0; j < 4; j++) d4[j] = s4[j];
  }
  __syncthreads();
  u16* img = vkt + ((((size_t)b * 8 + h) * 8 + kt) << 13);   // 8192 u16 / image
#pragma unroll
  for (int i = 0; i < 4; i++) {
    int c = tid * 4 + i;                 // chunk index 0..1023
    int dd = c >> 4, chsw = c & 15;
    int ch = chsw ^ (dd & 15);
    u16 tmp[8];
#pragma unroll
    for (int p = 0; p < 8; p++) {
      int col = ch * 8 + p;
      int g = col >> 5, kl = col & 31;
      int kph = ((kl >> 2) & 1) * 16 + ((kl >> 4) & 1) * 8 + ((kl >> 3) & 1) * 4 + (kl & 3);
      tmp[p] = Vn[(g * 32 + kph) * 64 + dd];
    }
    *(uint4*)&img[c * 8] = *(const uint4*)tmp;
  }
}

// ---------------- flash attention v4 ----------------
// Grid (4, 32, 4) = 512 blocks = 2/CU. Two q-tiles per block (qtA=bx, qtB=7-bx):
// 9 tile-steps per block, K/V staged once for both. Transposed-score form,
// max-free exp2 softmax, P kept in registers via the k-permutation baked into
// the VkT images. K and VT double-buffered pure DMA. One barrier/iter.
// LDS: Ks 2x16KB + VT 2x16KB = 64KB -> 2 blocks/CU. T5 setprio on MFMA clusters.
__global__ __launch_bounds__(256, 2) void flash_attn(const u16* __restrict__ qkv,
                                                     const u16* __restrict__ vkt,
                                                     u16* __restrict__ attn) {
  __shared__ u16 Ks[2][128 * 64];
  __shared__ u16 VT[2][64 * 128];

  const int tid = threadIdx.x;
  const int lane = tid & 63, wave = tid >> 6;
  const int quad = lane >> 4, l16 = lane & 15;
  const int qtA = blockIdx.x, qtB = 7 - blockIdx.x;
  const int h = blockIdx.y, b = blockIdx.z, kvh = h >> 2;
  const size_t tokBase = (size_t)b * 1024;
  const int qcol = h * 64, kcol = 2048 + kvh * 64;
  const int srow = tid >> 3, spc = tid & 7, ssc = spc ^ (srow & 7);

  auto stageK = [&](const u16* gbase, u16* L) {   // natural 128x64, swizzled chunks
#pragma unroll
    for (int i = 0; i < 4; i++)
      ld16_lds(gbase + (size_t)(srow + i * 32) * 3072 + ssc * 8, &L[tid * 8 + i * 2048]);
  };
  const u16* vimg = vkt + (((size_t)b * 8 + kvh) << 16);
  auto stageV = [&](int kt, u16* L) {             // pre-swizzled image: linear copy
    const u16* g = vimg + ((size_t)kt << 13);
#pragma unroll
    for (int i = 0; i < 4; i++)
      ld16_lds(g + i * 2048 + tid * 8, &L[tid * 8 + i * 2048]);
  };

  // ---- stage both Q tiles into the K buffers, extract fragments ----
  stageK(qkv + (tokBase + qtA * 128) * 3072 + qcol, Ks[0]);
  stageK(qkv + (tokBase + qtB * 128) * 3072 + qcol, Ks[1]);
  __syncthreads();
  bf16x8 qfA[2][2], qfB[2][2];   // B-frag: n=q=l16, kdim=d contiguous
#pragma unroll
  for (int nq = 0; nq < 2; nq++) {
    int qrow = wave * 32 + nq * 16 + l16;
#pragma unroll
    for (int ks = 0; ks < 2; ks++) {
      int c = (ks * 4 + quad) ^ (qrow & 7);
      qfA[nq][ks] = *(const bf16x8*)&Ks[0][qrow * 64 + c * 8];
      qfB[nq][ks] = *(const bf16x8*)&Ks[1][qrow * 64 + c * 8];
    }
  }
  __syncthreads();   // Q reads done before K DMA overwrites

  float lA[2] = {0.f, 0.f}, lB[2] = {0.f, 0.f};
  f32x4 oA[4][2] = {}, oB[4][2] = {};   // O^T: d=md*16+quad*4+r, q=nq*16+l16

  auto proc = [&](const bf16x8 (&kf)[2][2], const bf16x8 (&va)[4], const bf16x8 (&qf)[2][2],
                  f32x4 (&o)[4][2], float (&lacc)[2], bool msk, int c) {
    f32x4 s[2][2] = {};   // [nq][mkl]: k = (c*2+mkl)*16 + quad*4 + r, q = nq*16+l16
    __builtin_amdgcn_s_setprio(1);
#pragma unroll
    for (int mkl = 0; mkl < 2; mkl++)
#pragma unroll
      for (int ks = 0; ks < 2; ks++) {
        s[0][mkl] = __builtin_amdgcn_mfma_f32_16x16x32_bf16(kf[mkl][ks], qf[0][ks], s[0][mkl], 0, 0, 0);
        s[1][mkl] = __builtin_amdgcn_mfma_f32_16x16x32_bf16(kf[mkl][ks], qf[1][ks], s[1][mkl], 0, 0, 0);
      }
    __builtin_amdgcn_s_setprio(0);
    if (msk) {
#pragma unroll
      for (int nq = 0; nq < 2; nq++) {
        int q = wave * 32 + nq * 16 + l16;
#pragma unroll
        for (int mkl = 0; mkl < 2; mkl++)
#pragma unroll
          for (int r = 0; r < 4; r++)
            if ((c * 2 + mkl) * 16 + quad * 4 + r > q) s[nq][mkl][r] = -3e38f;
      }
    }
    bf16x8 pf[2];
#pragma unroll
    for (int nq = 0; nq < 2; nq++) {
      float a0 = 0.f;
#pragma unroll
      for (int mkl = 0; mkl < 2; mkl++)
#pragma unroll
        for (int r = 0; r < 4; r++) {
          float p = __builtin_amdgcn_exp2f(s[nq][mkl][r]);
          s[nq][mkl][r] = p;
          a0 += p;
        }
      lacc[nq] += a0;
      pf[nq][0] = (__bf16)s[nq][0][0]; pf[nq][1] = (__bf16)s[nq][0][1];
      pf[nq][2] = (__bf16)s[nq][0][2]; pf[nq][3] = (__bf16)s[nq][0][3];
      pf[nq][4] = (__bf16)s[nq][1][0]; pf[nq][5] = (__bf16)s[nq][1][1];
      pf[nq][6] = (__bf16)s[nq][1][2]; pf[nq][7] = (__bf16)s[nq][1][3];
    }
    __builtin_amdgcn_s_setprio(1);
#pragma unroll
    for (int md = 0; md < 4; md++) {
      o[md][0] = __builtin_amdgcn_mfma_f32_16x16x32_bf16(va[md], pf[0], o[md][0], 0, 0, 0);
      o[md][1] = __builtin_amdgcn_mfma_f32_16x16x32_bf16(va[md], pf[1], o[md][1], 0, 0, 0);
    }
    __builtin_amdgcn_s_setprio(0);
  };

  // ---- main loop: double-buffered K + VT DMA, one barrier per iteration ----
  stageK(qkv + tokBase * 3072 + kcol, Ks[0]);
  stageV(0, VT[0]);

  for (int kt = 0; kt <= qtB; kt++) {
    const int cur = kt & 1;
    __syncthreads();   // drains DMA for kt; all waves done with bufs[1-cur]
    if (kt < qtB) {
      stageK(qkv + (tokBase + (kt + 1) * 128) * 3072 + kcol, Ks[1 - cur]);
      stageV(kt + 1, VT[1 - cur]);
    }
    const bool doA = (kt <= qtA), mA = (kt == qtA), mB = (kt == qtB);
    const u16* K = Ks[cur];
    const u16* V = VT[cur];
#pragma unroll
    for (int c = 0; c < 4; c++) {
      bf16x8 kf[2][2];   // A-frag: m=krow=mk*16+l16, kdim=d
#pragma unroll
      for (int mkl = 0; mkl < 2; mkl++) {
        int krow = (c * 2 + mkl) * 16 + l16;
#pragma unroll
        for (int ks = 0; ks < 2; ks++)
          kf[mkl][ks] = *(const bf16x8*)&K[krow * 64 + ((ks * 4 + quad) ^ (krow & 7)) * 8];
      }
      bf16x8 va[4];      // A-frag V^T: m=d=md*16+l16, k-chunk c
#pragma unroll
      for (int md = 0; md < 4; md++) {
        int dd = md * 16 + l16;
        va[md] = *(const bf16x8*)&V[dd * 128 + ((c * 4 + quad) ^ l16) * 8];
      }
      proc(kf, va, qfB, oB, lB, mB, c);
      if (doA) proc(kf, va, qfA, oA, lA, mA, c);
    }
  }

  // ---- epilogue: reduce l across quads (2 shfls), O/l, b64 stores ----
  auto epilogue = [&](const f32x4 (&o)[4][2], const float (&lacc)[2], int qt_tile) {
#pragma unroll
    for (int nq = 0; nq < 2; nq++) {
      float l = lacc[nq];
      l += __shfl_xor(l, 16);
      l += __shfl_xor(l, 32);
      float inv = 1.0f / l;
      int t = qt_tile * 128 + wave * 32 + nq * 16 + l16;
      size_t rowOff = (tokBase + t) * 2048 + qcol;
#pragma unroll
      for (int md = 0; md < 4; md++) {
        bf16x4 w;
        w[0] = (__bf16)(o[md][nq][0] * inv);
        w[1] = (__bf16)(o[md][nq][1] * inv);
        w[2] = (__bf16)(o[md][nq][2] * inv);
        w[3] = (__bf16)(o[md][nq][3] * inv);
        *(bf16x4*)&attn[rowOff + md * 16 + quad * 4] = w;
      }
    }
  };
  epilogue(oB, lB, qtB);
  epilogue(oA, lA, qtA);
}

// ---------------- launch ----------------
extern "C" void kernel_launch(void* const* d_in, const int* in_sizes, int n_in,
                              void* d_out, int out_size, void* d_ws, size_t ws_size,
                              hipStream_t stream) {
  const float* hs = (const float*)d_in[0];
  const float* cs = (const float*)d_in[1];
  const float* sn = (const float*)d_in[2];
  const float* Wq = (const float*)d_in[3];
  const float* Wk = (const float*)d_in[4];
  const float* Wv = (const float*)d_in[5];
  const float* Wo = (const float*)d_in[6];
  float* out = (float*)d_out;

  char* ws = (char*)d_ws;
  u16* hsB   = (u16*)(ws);                  // 4096x2048 bf16 (dead after qkv GEMM)
  u16* vkt   = (u16*)(ws);                  // 4MB VkT images, built after qkv GEMM
  u16* wqkvT = (u16*)(ws + 16777216);       // 3072x2048 bf16 [WqT;WkT;WvT]
  u16* woT   = (u16*)(ws + 29360128);       // 2048x2048 bf16
  u16* qkv   = (u16*)(ws + 37748736);       // 4096x3072 bf16
  u16* attnB = (u16*)(ws + 62914560);       // 4096x2048 bf16

  // attention scale folded into Wq: 1/8 * log2(e)  (rope commutes with the scale)
  const float QSCALE = 0.18033688011112042f;

  // fused prep: convert (8192 blocks) + Wq (4096) + Wk (1024) + Wv (1024) + Wo (4096)
  prep<<<18432, 256, 0, stream>>>(hs, hsB, Wq, Wk, Wv, Wo, wqkvT, woT, QSCALE);

  // QKV: 128x192 tile, read-hoisted pipeline, grid 16x32 = 512 = 2/CU.
  gemm3<u16, 192><<<dim3(16, 32), 256, 0, stream>>>(hsB, wqkvT, qkv, 4096, 3072, 2048);
  // RoPE Q+K in-place + V images.
  rope_vkt<<<dim3(8, 32, 4), 256, 0, stream>>>(qkv, vkt, cs, sn);
  flash_attn<<<dim3(4, 32, 4), 256, 0, stream>>>(qkv, vkt, attnB);
  // Wo: 128x128 tile, grid 16x32 = 512 = 2/CU.
  gemm3<float, 128><<<dim3(16, 32), 256, 0, stream>>>(attnB, woT, out, 4096, 2048, 2048);
}

// Round 8
// 462.291 us; speedup vs baseline: 1.1131x; 1.1131x over previous
//
#include <hip/hip_runtime.h>
#include <type_traits>

// Problem constants (ExaoneFlashAttention): B=4, S=1024, T=4096, D_MODEL=2048,
// H=32, KVH=8, HD=64, GROUPS=4, SCALE=1/8. All bf16 MFMA, f32 accum.
// Attention scale * log2(e) folded into Wq transpose -> softmax in exp2 domain.
// Max-free softmax (logits bounded). RoPE applied by rope_vkt pre-pass (in-place
// on qkv; QK^T invariant under common d-relabeling, rope commutes with Q scale).

typedef __bf16 bf16x8 __attribute__((ext_vector_type(8)));
typedef __bf16 bf16x4 __attribute__((ext_vector_type(4)));
typedef float f32x4 __attribute__((ext_vector_type(4)));
typedef unsigned short u16;
typedef unsigned int u32;

#define DEVI __device__ __forceinline__

DEVI u16 f2bf(float f) {           // RNE f32->bf16 (finite inputs)
  u32 u = __builtin_bit_cast(u32, f);
  u += 0x7FFF + ((u >> 16) & 1);
  return (u16)(u >> 16);
}

// async global->LDS, 16B per lane. LDS dest must be wave-uniform base + lane*16.
DEVI void ld16_lds(const void* g, void* l) {
  __builtin_amdgcn_global_load_lds((const __attribute__((address_space(1))) u32*)g,
                                   (__attribute__((address_space(3))) u32*)l, 16, 0, 0);
}

DEVI void waitvm0() { asm volatile("s_waitcnt vmcnt(0)" ::: "memory"); }
DEVI void lgkm0() {                     // rule #18: sched_barrier after the wait
  asm volatile("s_waitcnt lgkmcnt(0)" ::: "memory");
  __builtin_amdgcn_sched_barrier(0);
}
DEVI void barrier() { __builtin_amdgcn_s_barrier(); }

// ---------------- fused prep: f32->bf16 convert + 4 weight transposes -------------------
__global__ __launch_bounds__(256) void prep(const float* __restrict__ hs, u16* __restrict__ hsB,
                                            const float* __restrict__ Wq, const float* __restrict__ Wk,
                                            const float* __restrict__ Wv, const float* __restrict__ Wo,
                                            u16* __restrict__ wqkvT, u16* __restrict__ woT,
                                            float qscale) {
  int b = blockIdx.x;
  if (b < 8192) {                      // ---- convert hs (4096x2048 f32) -> hsB bf16 ----
    int i = b * 256 + threadIdx.x;
    float4 v = ((const float4*)hs)[i];
    ushort4 o;
    o.x = f2bf(v.x); o.y = f2bf(v.y); o.z = f2bf(v.z); o.w = f2bf(v.w);
    ((ushort4*)hsB)[i] = o;
    return;
  }
  b -= 8192;
  const float* src; u16* dst; int R, C, bx, by; float sc = 1.0f;
  if (b < 4096)      { src = Wq; dst = wqkvT;                         R = 2048; C = 2048; bx = b & 63; by = b >> 6; sc = qscale; }
  else if (b < 5120) { b -= 4096; src = Wk; dst = wqkvT + (size_t)2048 * 2048; R = 2048; C = 512; bx = b & 15; by = b >> 4; }
  else if (b < 6144) { b -= 5120; src = Wv; dst = wqkvT + (size_t)2560 * 2048; R = 2048; C = 512; bx = b & 15; by = b >> 4; }
  else               { b -= 6144; src = Wo; dst = woT;                R = 2048; C = 2048; bx = b & 63; by = b >> 6; }
  __shared__ float tile[32][33];
  int c0 = bx * 32, r0 = by * 32;
  int tx = threadIdx.x & 31, ty = threadIdx.x >> 5;   // ty 0..7
#pragma unroll
  for (int i = 0; i < 32; i += 8)
    tile[ty + i][tx] = src[(size_t)(r0 + ty + i) * C + (c0 + tx)];
  __syncthreads();
#pragma unroll
  for (int i = 0; i < 32; i += 8)
    dst[(size_t)(c0 + ty + i) * R + (r0 + tx)] = f2bf(tile[tx][ty + i] * sc);
}

// ---------------- GEMM v8: read-hoisted pipeline, manual 2-tile unroll ------------------
// C(MxN) = A(MxK) * BT(NxK)^T, bf16 in, f32 acc. BM=128 x BN (192 QKV / 128 Wo),
// BK=64, 256 thr = 4 waves (2M x 2N), wave tile 64 x BN/2 (interleaved halves).
// LDS 80/64 KB -> 2 blocks/CU. Round-7 lesson (rule #20): af[s] with runtime s went
// to SCRATCH (538 MB WRITE_SIZE, 11% MfmaUtil). v8 hand-writes the two-tile loop
// body with NAMED register sets — afE/afO ping-pong, b0/b1 — and explicit LDS
// buffer pointers, so every index is compile-time and everything stays in regs.
// Schedule per half (tile t, frags for t already in regs):
//   stage(t+2) -> buf[t&1]                (tile-t LDS dead: reads done at t-1)
//   ldAF(next-af, buf[t+1&1])             (8 ds_read, complete under mm0)
//   mm0: af x b0  (24/16 MFMA, setprio)
//   ldB(b0 <- tile t+1)                   (WAR: ordered after mm0 by regs)
//   mm1: af x b1
//   ldB(b1 <- tile t+1)
//   waitvm0 (stage(t+2) landed, ~1-half cover + 2nd block/CU hides rest)
//   lgkm0 (frag reads t+1 done) ; barrier (publish before buf[t+1&1] restage)
// Prologue drains vmcnt(0) for BOTH initial stages before any read (r7 race fix).
// Regs: afE+afO 64 + b0+b1 48 VGPR + acc 96 AGPR ~ 230 unified — fits 2 waves/SIMD.
// T2 chunk swizzle unchanged; T1 XCD swizzle nwg=512 %8==0.
template <typename OutT, int BN>
__global__ __launch_bounds__(256, 2) void gemm4(const u16* __restrict__ A,
                                                const u16* __restrict__ BT,
                                                OutT* __restrict__ C, int M, int N, int K) {
  constexpr int NF = BN / 32;         // n-frags per wave: 6 (192) / 4 (128)
  constexpr int NH = NF / 2;          // frags per n-half: 3 / 2
  constexpr int HW = BN / 2;          // B half rows: 96 / 64
  constexpr int SW = HW / 2;          // per-wave span within a half: 48 / 32
  constexpr int LB0 = BN / 64;        // B-half stage loads/thr: 3 / 2
  __shared__ u16 As[2][128 * 64];
  __shared__ u16 Bs[2][BN * 64];
  const int tid = threadIdx.x;
  const int lane = tid & 63, wave = tid >> 6;
  const int quad = lane >> 4, l16 = lane & 15;

  // ---- XCD-aware block swizzle (bijective: nwg = 512, %8 == 0) ----
  const int nwg = gridDim.x * gridDim.y;
  const int bid = blockIdx.y * gridDim.x + blockIdx.x;
  const int swz = (bid & 7) * (nwg >> 3) + (bid >> 3);
  const int m0 = (swz / gridDim.x) * 128, n0 = (swz % gridDim.x) * BN;
  const int wr = wave >> 1, wc = wave & 1;   // 2M x 2N wave grid

  f32x4 acc[4][NF] = {};

  // ---- stage one full K-tile t into explicit buffers (A: 4 loads/thr, B: 2*LB0) ----
  auto stage = [&](int t, u16* Ad, u16* Bd) {
    {
      const u16* G = A + (size_t)m0 * K + t * 64;
#pragma unroll
      for (int i = 0; i < 4; ++i) {
        int id = i * 256 + tid, row = id >> 3, ch = id & 7;
        ld16_lds(G + (size_t)row * K + (ch ^ (row & 7)) * 8, Ad + id * 8);
      }
    }
#pragma unroll
    for (int h = 0; h < 2; ++h) {
      const u16* G = BT + (size_t)(n0 + h * HW) * K + t * 64;
#pragma unroll
      for (int i = 0; i < LB0; ++i) {
        int id = i * 256 + tid, row = id >> 3, ch = id & 7;
        // h*HW multiple of 8 -> (local row & 7) == (global row & 7)
        ld16_lds(G + (size_t)row * K + (ch ^ (row & 7)) * 8, Bd + (h * HW * 64) + id * 8);
      }
    }
  };

  // ---- named register fragments: afE/afO ping-pong, b0/b1 (all static indices) ----
  bf16x8 afE[4][2], afO[4][2], b0[NH][2], b1[NH][2];
  auto ldAF = [&](bf16x8 (&a)[4][2], const u16* Ab) {
#pragma unroll
    for (int i = 0; i < 4; ++i)
#pragma unroll
      for (int ks = 0; ks < 2; ++ks) {
        int r = wr * 64 + i * 16 + l16;
        a[i][ks] = *(const bf16x8*)&Ab[r * 64 + (((ks * 4 + quad) ^ (r & 7)) * 8)];
      }
  };
  auto ldB = [&](bf16x8 (&bv)[NH][2], int half, const u16* Bb) {
#pragma unroll
    for (int j = 0; j < NH; ++j)
#pragma unroll
      for (int ks = 0; ks < 2; ++ks) {
        int rb = half * HW + wc * SW + j * 16 + l16;
        bv[j][ks] = *(const bf16x8*)&Bb[rb * 64 + (((ks * 4 + quad) ^ (rb & 7)) * 8)];
      }
  };
  auto mmh = [&](const bf16x8 (&a)[4][2], const bf16x8 (&bv)[NH][2], int jo) {
    __builtin_amdgcn_s_setprio(1);
#pragma unroll
    for (int i = 0; i < 4; ++i)
#pragma unroll
      for (int j = 0; j < NH; ++j)
#pragma unroll
        for (int ks = 0; ks < 2; ++ks)
          acc[i][jo + j] =
              __builtin_amdgcn_mfma_f32_16x16x32_bf16(a[i][ks], bv[j][ks], acc[i][jo + j], 0, 0, 0);
    __builtin_amdgcn_s_setprio(0);
  };

  const int NT = K / 64;   // 32 (even) for both GEMMs

  // ---- prologue: stage tiles 0,1; FULL drain (r7 race fix); read tile-0 frags ----
  stage(0, As[0], Bs[0]);
  stage(1, As[1], Bs[1]);
  waitvm0();
  barrier();
  ldAF(afE, As[0]); ldB(b0, 0, Bs[0]); ldB(b1, 1, Bs[0]);
  lgkm0();
  barrier();                // all waves' tile-0 reads done (loop restages buf0)

#pragma unroll 1
  for (int tt = 0; tt < NT; tt += 2) {
    // ======== half 1: compute tile tt (afE/b0/b1), prefetch tile tt+1 frags ========
    if (tt + 2 < NT) stage(tt + 2, As[0], Bs[0]);   // buf0: tile tt dead
    ldAF(afO, As[1]);                               // tile tt+1 A-frags (under mm0)
    mmh(afE, b0, 0);
    ldB(b0, 0, Bs[1]);                              // tile tt+1 B-half0 (under mm1)
    mmh(afE, b1, NH);
    ldB(b1, 1, Bs[1]);                              // tile tt+1 B-half1
    waitvm0();                                      // stage(tt+2) landed
    lgkm0();                                        // tile tt+1 frag reads done
    barrier();                                      // publish: buf1 may be restaged
    // ======== half 2: compute tile tt+1 (afO/b0/b1), prefetch tile tt+2 frags ======
    if (tt + 2 < NT) {
      stage(tt + 3, As[1], Bs[1]);                  // buf1: tile tt+1 dead
      ldAF(afE, As[0]);                             // tile tt+2 A-frags
      mmh(afO, b0, 0);
      ldB(b0, 0, Bs[0]);
      mmh(afO, b1, NH);
      ldB(b1, 1, Bs[0]);
      waitvm0();                                    // stage(tt+3) landed
      lgkm0();                                      // tile tt+2 frag reads done
      barrier();
    } else {                                        // final tile: no more staging/reads
      mmh(afO, b0, 0);
      mmh(afO, b1, NH);
    }
  }

  // ---- epilogue: C/D layout col=lane&15, row=quad*4+r ----
#pragma unroll
  for (int i = 0; i < 4; ++i) {
    int row = m0 + wr * 64 + i * 16 + quad * 4;
#pragma unroll
    for (int j = 0; j < NF; ++j) {
      int half = j / NH, jj = j % NH;
      int col = n0 + half * HW + wc * SW + jj * 16 + l16;
#pragma unroll
      for (int r = 0; r < 4; ++r) {
        size_t off = (size_t)(row + r) * N + col;
        if constexpr (sizeof(OutT) == 2) C[off] = f2bf(acc[i][j][r]);
        else C[off] = acc[i][j][r];
      }
    }
  }
}

// ---------------- rope_vkt: RoPE Q/K in-place + V tile images ---------------------------
// Grid (8 kt, 32 h, 4 b). Every block ropes the Q tile [128 tok x 64] of head h.
// Blocks with h<8 additionally rope the K tile of kvh=h and build the V image
// (transposed, chunk-swizzled, k-permuted). RoPE pair (d, d+32) is in-row ->
// one thread owns a full pair group; cs/sn indexed by global token.
__global__ __launch_bounds__(256) void rope_vkt(u16* __restrict__ qkv,
                                                u16* __restrict__ vkt,
                                                const float* __restrict__ cs,
                                                const float* __restrict__ sn) {
  const int kt = blockIdx.x, h = blockIdx.y, b = blockIdx.z;
  const int tid = threadIdx.x;
  const size_t tok0 = (size_t)b * 1024 + (size_t)kt * 128;

  // ---- RoPE: 2 threads per row, 2 pair-groups (8 pairs each) per thread ----
  {
    const int r = tid >> 1, hf = tid & 1;
    const size_t t = tok0 + r;
    const float* cr = cs + t * 32;
    const float* sr = sn + t * 32;
    u16* qrow = qkv + t * 3072 + h * 64;
    u16* krow = qkv + t * 3072 + 2048 + h * 64;   // used only when h<8
#pragma unroll
    for (int gg = 0; gg < 2; ++gg) {
      const int g = hf * 2 + gg;                  // pair-group 0..3 (d = g*8+e)
      float cv[8], sv[8];
#pragma unroll
      for (int e = 0; e < 8; ++e) { cv[e] = cr[g * 8 + e]; sv[e] = sr[g * 8 + e]; }
      {
        bf16x8 a = *(bf16x8*)&qrow[g * 8];
        bf16x8 b2 = *(bf16x8*)&qrow[g * 8 + 32];
#pragma unroll
        for (int e = 0; e < 8; ++e) {
          float x1 = (float)a[e], x2 = (float)b2[e];
          a[e] = (__bf16)(x1 * cv[e] - x2 * sv[e]);
          b2[e] = (__bf16)(x2 * cv[e] + x1 * sv[e]);
        }
        *(bf16x8*)&qrow[g * 8] = a;
        *(bf16x8*)&qrow[g * 8 + 32] = b2;
      }
      if (h < 8) {
        bf16x8 a = *(bf16x8*)&krow[g * 8];
        bf16x8 b2 = *(bf16x8*)&krow[g * 8 + 32];
#pragma unroll
        for (int e = 0; e < 8; ++e) {
          float x1 = (float)a[e], x2 = (float)b2[e];
          a[e] = (__bf16)(x1 * cv[e] - x2 * sv[e]);
          b2[e] = (__bf16)(x2 * cv[e] + x1 * sv[e]);
        }
        *(bf16x8*)&krow[g * 8] = a;
        *(bf16x8*)&krow[g * 8 + 32] = b2;
      }
    }
  }
  if (h >= 8) return;

  // ---- V image build (kvh = h) ----
  __shared__ u16 Vn[128 * 64];
  const u16* src = qkv + tok0 * 3072 + 2560 + h * 64;
  {
    int tok = tid >> 1, hf = tid & 1;
    const uint4* s4 = (const uint4*)(src + (size_t)tok * 3072 + hf * 32);
    uint4* d4 = (uint4*)&Vn[tok * 64 + hf * 32];
#pragma unroll
    for (int j = 0; j < 4; j++) d4[j] = s4[j];
  }
  __syncthreads();
  u16* img = vkt + ((((size_t)b * 8 + h) * 8 + kt) << 13);   // 8192 u16 / image
#pragma unroll
  for (int i = 0; i < 4; i++) {
    int c = tid * 4 + i;                 // chunk index 0..1023
    int dd = c >> 4, chsw = c & 15;
    int ch = chsw ^ (dd & 15);
    u16 tmp[8];
#pragma unroll
    for (int p = 0; p < 8; p++) {
      int col = ch * 8 + p;
      int g = col >> 5, kl = col & 31;
      int kph = ((kl >> 2) & 1) * 16 + ((kl >> 4) & 1) * 8 + ((kl >> 3) & 1) * 4 + (kl & 3);
      tmp[p] = Vn[(g * 32 + kph) * 64 + dd];
    }
    *(uint4*)&img[c * 8] = *(const uint4*)tmp;
  }
}

// ---------------- flash attention v4 ----------------
// Grid (4, 32, 4) = 512 blocks = 2/CU. Two q-tiles per block (qtA=bx, qtB=7-bx):
// 9 tile-steps per block, K/V staged once for both. Transposed-score form,
// max-free exp2 softmax, P kept in registers via the k-permutation baked into
// the VkT images. K and VT double-buffered pure DMA. One barrier/iter.
// LDS: Ks 2x16KB + VT 2x16KB = 64KB -> 2 blocks/CU. T5 setprio on MFMA clusters.
__global__ __launch_bounds__(256, 2) void flash_attn(const u16* __restrict__ qkv,
                                                     const u16* __restrict__ vkt,
                                                     u16* __restrict__ attn) {
  __shared__ u16 Ks[2][128 * 64];
  __shared__ u16 VT[2][64 * 128];

  const int tid = threadIdx.x;
  const int lane = tid & 63, wave = tid >> 6;
  const int quad = lane >> 4, l16 = lane & 15;
  const int qtA = blockIdx.x, qtB = 7 - blockIdx.x;
  const int h = blockIdx.y, b = blockIdx.z, kvh = h >> 2;
  const size_t tokBase = (size_t)b * 1024;
  const int qcol = h * 64, kcol = 2048 + kvh * 64;
  const int srow = tid >> 3, spc = tid & 7, ssc = spc ^ (srow & 7);

  auto stageK = [&](const u16* gbase, u16* L) {   // natural 128x64, swizzled chunks
#pragma unroll
    for (int i = 0; i < 4; i++)
      ld16_lds(gbase + (size_t)(srow + i * 32) * 3072 + ssc * 8, &L[tid * 8 + i * 2048]);
  };
  const u16* vimg = vkt + (((size_t)b * 8 + kvh) << 16);
  auto stageV = [&](int kt, u16* L) {             // pre-swizzled image: linear copy
    const u16* g = vimg + ((size_t)kt << 13);
#pragma unroll
    for (int i = 0; i < 4; i++)
      ld16_lds(g + i * 2048 + tid * 8, &L[tid * 8 + i * 2048]);
  };

  // ---- stage both Q tiles into the K buffers, extract fragments ----
  stageK(qkv + (tokBase + qtA * 128) * 3072 + qcol, Ks[0]);
  stageK(qkv + (tokBase + qtB * 128) * 3072 + qcol, Ks[1]);
  __syncthreads();
  bf16x8 qfA[2][2], qfB[2][2];   // B-frag: n=q=l16, kdim=d contiguous
#pragma unroll
  for (int nq = 0; nq < 2; nq++) {
    int qrow = wave * 32 + nq * 16 + l16;
#pragma unroll
    for (int ks = 0; ks < 2; ks++) {
      int c = (ks * 4 + quad) ^ (qrow & 7);
      qfA[nq][ks] = *(const bf16x8*)&Ks[0][qrow * 64 + c * 8];
      qfB[nq][ks] = *(const bf16x8*)&Ks[1][qrow * 64 + c * 8];
    }
  }
  __syncthreads();   // Q reads done before K DMA overwrites

  float lA[2] = {0.f, 0.f}, lB[2] = {0.f, 0.f};
  f32x4 oA[4][2] = {}, oB[4][2] = {};   // O^T: d=md*16+quad*4+r, q=nq*16+l16

  auto proc = [&](const bf16x8 (&kf)[2][2], const bf16x8 (&va)[4], const bf16x8 (&qf)[2][2],
                  f32x4 (&o)[4][2], float (&lacc)[2], bool msk, int c) {
    f32x4 s[2][2] = {};   // [nq][mkl]: k = (c*2+mkl)*16 + quad*4 + r, q = nq*16+l16
    __builtin_amdgcn_s_setprio(1);
#pragma unroll
    for (int mkl = 0; mkl < 2; mkl++)
#pragma unroll
      for (int ks = 0; ks < 2; ks++) {
        s[0][mkl] = __builtin_amdgcn_mfma_f32_16x16x32_bf16(kf[mkl][ks], qf[0][ks], s[0][mkl], 0, 0, 0);
        s[1][mkl] = __builtin_amdgcn_mfma_f32_16x16x32_bf16(kf[mkl][ks], qf[1][ks], s[1][mkl], 0, 0, 0);
      }
    __builtin_amdgcn_s_setprio(0);
    if (msk) {
#pragma unroll
      for (int nq = 0; nq < 2; nq++) {
        int q = wave * 32 + nq * 16 + l16;
#pragma unroll
        for (int mkl = 0; mkl < 2; mkl++)
#pragma unroll
          for (int r = 0; r < 4; r++)
            if ((c * 2 + mkl) * 16 + quad * 4 + r > q) s[nq][mkl][r] = -3e38f;
      }
    }
    bf16x8 pf[2];
#pragma unroll
    for (int nq = 0; nq < 2; nq++) {
      float a0 = 0.f;
#pragma unroll
      for (int mkl = 0; mkl < 2; mkl++)
#pragma unroll
        for (int r = 0; r < 4; r++) {
          float p = __builtin_amdgcn_exp2f(s[nq][mkl][r]);
          s[nq][mkl][r] = p;
          a0 += p;
        }
      lacc[nq] += a0;
      pf[nq][0] = (__bf16)s[nq][0][0]; pf[nq][1] = (__bf16)s[nq][0][1];
      pf[nq][2] = (__bf16)s[nq][0][2]; pf[nq][3] = (__bf16)s[nq][0][3];
      pf[nq][4] = (__bf16)s[nq][1][0]; pf[nq][5] = (__bf16)s[nq][1][1];
      pf[nq][6] = (__bf16)s[nq][1][2]; pf[nq][7] = (__bf16)s[nq][1][3];
    }
    __builtin_amdgcn_s_setprio(1);
#pragma unroll
    for (int md = 0; md < 4; md++) {
      o[md][0] = __builtin_amdgcn_mfma_f32_16x16x32_bf16(va[md], pf[0], o[md][0], 0, 0, 0);
      o[md][1] = __builtin_amdgcn_mfma_f32_16x16x32_bf16(va[md], pf[1], o[md][1], 0, 0, 0);
    }
    __builtin_amdgcn_s_setprio(0);
  };

  // ---- main loop: double-buffered K + VT DMA, one barrier per iteration ----
  stageK(qkv + tokBase * 3072 + kcol, Ks[0]);
  stageV(0, VT[0]);

  for (int kt = 0; kt <= qtB; kt++) {
    const int cur = kt & 1;
    __syncthreads();   // drains DMA for kt; all waves done with bufs[1-cur]
    if (kt < qtB) {
      stageK(qkv + (tokBase + (kt + 1) * 128) * 3072 + kcol, Ks[1 - cur]);
      stageV(kt + 1, VT[1 - cur]);
    }
    const bool doA = (kt <= qtA), mA = (kt == qtA), mB = (kt == qtB);
    const u16* K = Ks[cur];
    const u16* V = VT[cur];
#pragma unroll
    for (int c = 0; c < 4; c++) {
      bf16x8 kf[2][2];   // A-frag: m=krow=mk*16+l16, kdim=d
#pragma unroll
      for (int mkl = 0; mkl < 2; mkl++) {
        int krow = (c * 2 + mkl) * 16 + l16;
#pragma unroll
        for (int ks = 0; ks < 2; ks++)
          kf[mkl][ks] = *(const bf16x8*)&K[krow * 64 + ((ks * 4 + quad) ^ (krow & 7)) * 8];
      }
      bf16x8 va[4];      // A-frag V^T: m=d=md*16+l16, k-chunk c
#pragma unroll
      for (int md = 0; md < 4; md++) {
        int dd = md * 16 + l16;
        va[md] = *(const bf16x8*)&V[dd * 128 + ((c * 4 + quad) ^ l16) * 8];
      }
      proc(kf, va, qfB, oB, lB, mB, c);
      if (doA) proc(kf, va, qfA, oA, lA, mA, c);
    }
  }

  // ---- epilogue: reduce l across quads (2 shfls), O/l, b64 stores ----
  auto epilogue = [&](const f32x4 (&o)[4][2], const float (&lacc)[2], int qt_tile) {
#pragma unroll
    for (int nq = 0; nq < 2; nq++) {
      float l = lacc[nq];
      l += __shfl_xor(l, 16);
      l += __shfl_xor(l, 32);
      float inv = 1.0f / l;
      int t = qt_tile * 128 + wave * 32 + nq * 16 + l16;
      size_t rowOff = (tokBase + t) * 2048 + qcol;
#pragma unroll
      for (int md = 0; md < 4; md++) {
        bf16x4 w;
        w[0] = (__bf16)(o[md][nq][0] * inv);
        w[1] = (__bf16)(o[md][nq][1] * inv);
        w[2] = (__bf16)(o[md][nq][2] * inv);
        w[3] = (__bf16)(o[md][nq][3] * inv);
        *(bf16x4*)&attn[rowOff + md * 16 + quad * 4] = w;
      }
    }
  };
  epilogue(oB, lB, qtB);
  epilogue(oA, lA, qtA);
}

// ---------------- launch ----------------
extern "C" void kernel_launch(void* const* d_in, const int* in_sizes, int n_in,
                              void* d_out, int out_size, void* d_ws, size_t ws_size,
                              hipStream_t stream) {
  const float* hs = (const float*)d_in[0];
  const float* cs = (const float*)d_in[1];
  const float* sn = (const float*)d_in[2];
  const float* Wq = (const float*)d_in[3];
  const float* Wk = (const float*)d_in[4];
  const float* Wv = (const float*)d_in[5];
  const float* Wo = (const float*)d_in[6];
  float* out = (float*)d_out;

  char* ws = (char*)d_ws;
  u16* hsB   = (u16*)(ws);                  // 4096x2048 bf16 (dead after qkv GEMM)
  u16* vkt   = (u16*)(ws);                  // 4MB VkT images, built after qkv GEMM
  u16* wqkvT = (u16*)(ws + 16777216);       // 3072x2048 bf16 [WqT;WkT;WvT]
  u16* woT   = (u16*)(ws + 29360128);       // 2048x2048 bf16
  u16* qkv   = (u16*)(ws + 37748736);       // 4096x3072 bf16
  u16* attnB = (u16*)(ws + 62914560);       // 4096x2048 bf16

  // attention scale folded into Wq: 1/8 * log2(e)  (rope commutes with the scale)
  const float QSCALE = 0.18033688011112042f;

  // fused prep: convert (8192 blocks) + Wq (4096) + Wk (1024) + Wv (1024) + Wo (4096)
  prep<<<18432, 256, 0, stream>>>(hs, hsB, Wq, Wk, Wv, Wo, wqkvT, woT, QSCALE);

  // QKV: 128x192 tile, read-hoisted pipeline, grid 16x32 = 512 = 2/CU.
  gemm4<u16, 192><<<dim3(16, 32), 256, 0, stream>>>(hsB, wqkvT, qkv, 4096, 3072, 2048);
  // RoPE Q+K in-place + V images.
  rope_vkt<<<dim3(8, 32, 4), 256, 0, stream>>>(qkv, vkt, cs, sn);
  flash_attn<<<dim3(4, 32, 4), 256, 0, stream>>>(qkv, vkt, attnB);
  // Wo: 128x128 tile, grid 16x32 = 512 = 2/CU.
  gemm4<float, 128><<<dim3(16, 32), 256, 0, stream>>>(attnB, woT, out, 4096, 2048, 2048);
}

// Round 9
// 259.690 us; speedup vs baseline: 1.9816x; 1.7802x over previous
//
#include <hip/hip_runtime.h>
#include <type_traits>

// Problem constants (ExaoneFlashAttention): B=4, S=1024, T=4096, D_MODEL=2048,
// H=32, KVH=8, HD=64, GROUPS=4, SCALE=1/8. All bf16 MFMA, f32 accum.
// Attention scale * log2(e) folded into Wq transpose -> softmax in exp2 domain.
// Max-free softmax (logits bounded). RoPE applied by rope_vkt pre-pass (in-place
// on qkv; QK^T invariant under common d-relabeling, rope commutes with Q scale).

typedef __bf16 bf16x8 __attribute__((ext_vector_type(8)));
typedef __bf16 bf16x4 __attribute__((ext_vector_type(4)));
typedef float f32x4 __attribute__((ext_vector_type(4)));
typedef unsigned short u16;
typedef unsigned int u32;

#define DEVI __device__ __forceinline__

DEVI u16 f2bf(float f) {           // RNE f32->bf16 (finite inputs)
  u32 u = __builtin_bit_cast(u32, f);
  u += 0x7FFF + ((u >> 16) & 1);
  return (u16)(u >> 16);
}

// async global->LDS, 16B per lane. LDS dest must be wave-uniform base + lane*16.
DEVI void ld16_lds(const void* g, void* l) {
  __builtin_amdgcn_global_load_lds((const __attribute__((address_space(1))) u32*)g,
                                   (__attribute__((address_space(3))) u32*)l, 16, 0, 0);
}

DEVI void waitvm0() { asm volatile("s_waitcnt vmcnt(0)" ::: "memory"); }
template <int N> DEVI void lgkmN() {   // counted DS wait (DS retires in order);
  if constexpr (N == 0) asm volatile("s_waitcnt lgkmcnt(0)" ::: "memory");
  else if constexpr (N == 4) asm volatile("s_waitcnt lgkmcnt(4)" ::: "memory");
  else if constexpr (N == 6) asm volatile("s_waitcnt lgkmcnt(6)" ::: "memory");
  else static_assert(N == 0, "unsupported lgkmcnt");
  __builtin_amdgcn_sched_barrier(0);   // rule #18
}
DEVI void barrier() { __builtin_amdgcn_s_barrier(); }

// ---------------- fused prep: f32->bf16 convert + 4 weight transposes -------------------
__global__ __launch_bounds__(256) void prep(const float* __restrict__ hs, u16* __restrict__ hsB,
                                            const float* __restrict__ Wq, const float* __restrict__ Wk,
                                            const float* __restrict__ Wv, const float* __restrict__ Wo,
                                            u16* __restrict__ wqkvT, u16* __restrict__ woT,
                                            float qscale) {
  int b = blockIdx.x;
  if (b < 8192) {                      // ---- convert hs (4096x2048 f32) -> hsB bf16 ----
    int i = b * 256 + threadIdx.x;
    float4 v = ((const float4*)hs)[i];
    ushort4 o;
    o.x = f2bf(v.x); o.y = f2bf(v.y); o.z = f2bf(v.z); o.w = f2bf(v.w);
    ((ushort4*)hsB)[i] = o;
    return;
  }
  b -= 8192;
  const float* src; u16* dst; int R, C, bx, by; float sc = 1.0f;
  if (b < 4096)      { src = Wq; dst = wqkvT;                         R = 2048; C = 2048; bx = b & 63; by = b >> 6; sc = qscale; }
  else if (b < 5120) { b -= 4096; src = Wk; dst = wqkvT + (size_t)2048 * 2048; R = 2048; C = 512; bx = b & 15; by = b >> 4; }
  else if (b < 6144) { b -= 5120; src = Wv; dst = wqkvT + (size_t)2560 * 2048; R = 2048; C = 512; bx = b & 15; by = b >> 4; }
  else               { b -= 6144; src = Wo; dst = woT;                R = 2048; C = 2048; bx = b & 63; by = b >> 6; }
  __shared__ float tile[32][33];
  int c0 = bx * 32, r0 = by * 32;
  int tx = threadIdx.x & 31, ty = threadIdx.x >> 5;   // ty 0..7
#pragma unroll
  for (int i = 0; i < 32; i += 8)
    tile[ty + i][tx] = src[(size_t)(r0 + ty + i) * C + (c0 + tx)];
  __syncthreads();
#pragma unroll
  for (int i = 0; i < 32; i += 8)
    dst[(size_t)(c0 + ty + i) * R + (r0 + tx)] = f2bf(tile[tx][ty + i] * sc);
}

// ---------------- GEMM v9: merged single-phase loop, r6 register footprint --------------
// C(MxN) = A(MxK) * BT(NxK)^T, bf16 in, f32 acc. BM=128 x BN (192 QKV / 128 Wo),
// BK=64, 256 thr = 4 waves (2M x 2N), wave tile 64 x BN/2 (interleaved halves).
// LDS 80/64 KB -> 2 blocks/CU. Lessons: r7/r8 register prefetch (af ping-pong)
// SPILLED (rule #20 r7; unified-budget overflow r8: 96 acc AGPR + ~130 arch VGPR
// > the 128 the compiler granted). v9 keeps r6's register set (af 32 + b0/b1 48,
// ~100 arch VGPR measured) and gets overlap from WAIT PLACEMENT instead:
//   iter t (buf=t&1):
//     ldA, ldB0, ldB1 (tile t, 20/16 ds_reads)
//     stage(t+1) -> buf^1          (full tile; region freed by last iter's barrier)
//     lgkmcnt(2*NH)                (counted: A+b0 done, b1 still in flight)
//     mm0 (24/16 MFMA, setprio)    (b1 latency hides under this)
//     lgkmcnt(0) ; mm1
//     waitvm(0) ; barrier          (single barrier+drain per K-tile; stage cover
//                                   = lgkm stall + 48 MFMA ~ 1200cy >= HBM ~900)
// vs r6: barriers/tile 2->1, read-stall windows 2->1, vmcnt waits 2->1.
// Counted-lgkm is an optimization only — compiler's own dependency waits are the
// correctness backstop if it reorders DS issue. All reads drain at lgkm0 before
// the closing barrier, so the next iteration may safely restage buf.
// T2 chunk swizzle: LDS[row][ch] = global chunk ch^(row&7) via pre-swizzled
// source, same XOR on read -> conflict-free ds_read_b128 (0 conflicts measured).
// T1 XCD swizzle: nwg=512 %8==0.
template <typename OutT, int BN>
__global__ __launch_bounds__(256, 2) void gemm5(const u16* __restrict__ A,
                                                const u16* __restrict__ BT,
                                                OutT* __restrict__ C, int M, int N, int K) {
  constexpr int NF = BN / 32;         // n-frags per wave: 6 (192) / 4 (128)
  constexpr int NH = NF / 2;          // frags per n-half: 3 / 2
  constexpr int HW = BN / 2;          // B half rows: 96 / 64
  constexpr int SW = HW / 2;          // per-wave span within a half: 48 / 32
  constexpr int LB0 = BN / 64;        // B-half stage loads/thr: 3 / 2
  __shared__ u16 As[2][128 * 64];
  __shared__ u16 Bs[2][BN * 64];
  const int tid = threadIdx.x;
  const int lane = tid & 63, wave = tid >> 6;
  const int quad = lane >> 4, l16 = lane & 15;

  // ---- XCD-aware block swizzle (bijective: nwg = 512, %8 == 0) ----
  const int nwg = gridDim.x * gridDim.y;
  const int bid = blockIdx.y * gridDim.x + blockIdx.x;
  const int swz = (bid & 7) * (nwg >> 3) + (bid >> 3);
  const int m0 = (swz / gridDim.x) * 128, n0 = (swz % gridDim.x) * BN;
  const int wr = wave >> 1, wc = wave & 1;   // 2M x 2N wave grid

  f32x4 acc[4][NF] = {};

  // ---- stage one full K-tile t into explicit buffers (A: 4 loads/thr, B: 2*LB0) ----
  auto stage = [&](int t, u16* Ad, u16* Bd) {
    {
      const u16* G = A + (size_t)m0 * K + t * 64;
#pragma unroll
      for (int i = 0; i < 4; ++i) {
        int id = i * 256 + tid, row = id >> 3, ch = id & 7;
        ld16_lds(G + (size_t)row * K + (ch ^ (row & 7)) * 8, Ad + id * 8);
      }
    }
#pragma unroll
    for (int h = 0; h < 2; ++h) {
      const u16* G = BT + (size_t)(n0 + h * HW) * K + t * 64;
#pragma unroll
      for (int i = 0; i < LB0; ++i) {
        int id = i * 256 + tid, row = id >> 3, ch = id & 7;
        // h*HW multiple of 8 -> (local row & 7) == (global row & 7)
        ld16_lds(G + (size_t)row * K + (ch ^ (row & 7)) * 8, Bd + (h * HW * 64) + id * 8);
      }
    }
  };

  // ---- register fragments: single sets (r6 footprint; fits, no spill) ----
  bf16x8 af[4][2], b0[NH][2], b1[NH][2];
  auto ldAF = [&](const u16* Ab) {
#pragma unroll
    for (int i = 0; i < 4; ++i)
#pragma unroll
      for (int ks = 0; ks < 2; ++ks) {
        int r = wr * 64 + i * 16 + l16;
        af[i][ks] = *(const bf16x8*)&Ab[r * 64 + (((ks * 4 + quad) ^ (r & 7)) * 8)];
      }
  };
  auto ldB = [&](bf16x8 (&bv)[NH][2], int half, const u16* Bb) {
#pragma unroll
    for (int j = 0; j < NH; ++j)
#pragma unroll
      for (int ks = 0; ks < 2; ++ks) {
        int rb = half * HW + wc * SW + j * 16 + l16;
        bv[j][ks] = *(const bf16x8*)&Bb[rb * 64 + (((ks * 4 + quad) ^ (rb & 7)) * 8)];
      }
  };
  auto mmh = [&](const bf16x8 (&bv)[NH][2], int jo) {   // 4 x NH x 2 MFMA (T5 wrap)
    __builtin_amdgcn_s_setprio(1);
#pragma unroll
    for (int i = 0; i < 4; ++i)
#pragma unroll
      for (int j = 0; j < NH; ++j)
#pragma unroll
        for (int ks = 0; ks < 2; ++ks)
          acc[i][jo + j] =
              __builtin_amdgcn_mfma_f32_16x16x32_bf16(af[i][ks], bv[j][ks], acc[i][jo + j], 0, 0, 0);
    __builtin_amdgcn_s_setprio(0);
  };

  const int NT = K / 64;   // 32 for both GEMMs

  // ---- prologue: stage tile 0, full drain, publish ----
  stage(0, As[0], Bs[0]);
  waitvm0();
  barrier();

#pragma unroll 2
  for (int t = 0; t < NT; ++t) {
    const int buf = t & 1;
    ldAF(As[buf]); ldB(b0, 0, Bs[buf]); ldB(b1, 1, Bs[buf]);   // 20/16 ds_reads
    if (t + 1 < NT) stage(t + 1, As[buf ^ 1], Bs[buf ^ 1]);    // vmcnt only
    lgkmN<2 * NH>();          // A + b0 complete; b1 flying under mm0
    mmh(b0, 0);
    lgkmN<0>();               // b1 complete (all tile-t reads done)
    mmh(b1, NH);
    if (t + 1 < NT) {
      waitvm0();              // stage(t+1) landed (cover ~ lgkm stall + 48 MFMA)
      barrier();              // publish; next iter may restage buf
    }
  }

  // ---- epilogue: C/D layout col=lane&15, row=quad*4+r ----
#pragma unroll
  for (int i = 0; i < 4; ++i) {
    int row = m0 + wr * 64 + i * 16 + quad * 4;
#pragma unroll
    for (int j = 0; j < NF; ++j) {
      int half = j / NH, jj = j % NH;
      int col = n0 + half * HW + wc * SW + jj * 16 + l16;
#pragma unroll
      for (int r = 0; r < 4; ++r) {
        size_t off = (size_t)(row + r) * N + col;
        if constexpr (sizeof(OutT) == 2) C[off] = f2bf(acc[i][j][r]);
        else C[off] = acc[i][j][r];
      }
    }
  }
}

// ---------------- rope_vkt: RoPE Q/K in-place + V tile images ---------------------------
// Grid (8 kt, 32 h, 4 b). Every block ropes the Q tile [128 tok x 64] of head h.
// Blocks with h<8 additionally rope the K tile of kvh=h and build the V image
// (transposed, chunk-swizzled, k-permuted). RoPE pair (d, d+32) is in-row ->
// one thread owns a full pair group; cs/sn indexed by global token.
__global__ __launch_bounds__(256) void rope_vkt(u16* __restrict__ qkv,
                                                u16* __restrict__ vkt,
                                                const float* __restrict__ cs,
                                                const float* __restrict__ sn) {
  const int kt = blockIdx.x, h = blockIdx.y, b = blockIdx.z;
  const int tid = threadIdx.x;
  const size_t tok0 = (size_t)b * 1024 + (size_t)kt * 128;

  // ---- RoPE: 2 threads per row, 2 pair-groups (8 pairs each) per thread ----
  {
    const int r = tid >> 1, hf = tid & 1;
    const size_t t = tok0 + r;
    const float* cr = cs + t * 32;
    const float* sr = sn + t * 32;
    u16* qrow = qkv + t * 3072 + h * 64;
    u16* krow = qkv + t * 3072 + 2048 + h * 64;   // used only when h<8
#pragma unroll
    for (int gg = 0; gg < 2; ++gg) {
      const int g = hf * 2 + gg;                  // pair-group 0..3 (d = g*8+e)
      float cv[8], sv[8];
#pragma unroll
      for (int e = 0; e < 8; ++e) { cv[e] = cr[g * 8 + e]; sv[e] = sr[g * 8 + e]; }
      {
        bf16x8 a = *(bf16x8*)&qrow[g * 8];
        bf16x8 b2 = *(bf16x8*)&qrow[g * 8 + 32];
#pragma unroll
        for (int e = 0; e < 8; ++e) {
          float x1 = (float)a[e], x2 = (float)b2[e];
          a[e] = (__bf16)(x1 * cv[e] - x2 * sv[e]);
          b2[e] = (__bf16)(x2 * cv[e] + x1 * sv[e]);
        }
        *(bf16x8*)&qrow[g * 8] = a;
        *(bf16x8*)&qrow[g * 8 + 32] = b2;
      }
      if (h < 8) {
        bf16x8 a = *(bf16x8*)&krow[g * 8];
        bf16x8 b2 = *(bf16x8*)&krow[g * 8 + 32];
#pragma unroll
        for (int e = 0; e < 8; ++e) {
          float x1 = (float)a[e], x2 = (float)b2[e];
          a[e] = (__bf16)(x1 * cv[e] - x2 * sv[e]);
          b2[e] = (__bf16)(x2 * cv[e] + x1 * sv[e]);
        }
        *(bf16x8*)&krow[g * 8] = a;
        *(bf16x8*)&krow[g * 8 + 32] = b2;
      }
    }
  }
  if (h >= 8) return;

  // ---- V image build (kvh = h) ----
  __shared__ u16 Vn[128 * 64];
  const u16* src = qkv + tok0 * 3072 + 2560 + h * 64;
  {
    int tok = tid >> 1, hf = tid & 1;
    const uint4* s4 = (const uint4*)(src + (size_t)tok * 3072 + hf * 32);
    uint4* d4 = (uint4*)&Vn[tok * 64 + hf * 32];
#pragma unroll
    for (int j = 0; j < 4; j++) d4[j] = s4[j];
  }
  __syncthreads();
  u16* img = vkt + ((((size_t)b * 8 + h) * 8 + kt) << 13);   // 8192 u16 / image
#pragma unroll
  for (int i = 0; i < 4; i++) {
    int c = tid * 4 + i;                 // chunk index 0..1023
    int dd = c >> 4, chsw = c & 15;
    int ch = chsw ^ (dd & 15);
    u16 tmp[8];
#pragma unroll
    for (int p = 0; p < 8; p++) {
      int col = ch * 8 + p;
      int g = col >> 5, kl = col & 31;
      int kph = ((kl >> 2) & 1) * 16 + ((kl >> 4) & 1) * 8 + ((kl >> 3) & 1) * 4 + (kl & 3);
      tmp[p] = Vn[(g * 32 + kph) * 64 + dd];
    }
    *(uint4*)&img[c * 8] = *(const uint4*)tmp;
  }
}

// ---------------- flash attention v4 ----------------
// Grid (4, 32, 4) = 512 blocks = 2/CU. Two q-tiles per block (qtA=bx, qtB=7-bx):
// 9 tile-steps per block, K/V staged once for both. Transposed-score form,
// max-free exp2 softmax, P kept in registers via the k-permutation baked into
// the VkT images. K and VT double-buffered pure DMA. One barrier/iter.
// LDS: Ks 2x16KB + VT 2x16KB = 64KB -> 2 blocks/CU. T5 setprio on MFMA clusters.
__global__ __launch_bounds__(256, 2) void flash_attn(const u16* __restrict__ qkv,
                                                     const u16* __restrict__ vkt,
                                                     u16* __restrict__ attn) {
  __shared__ u16 Ks[2][128 * 64];
  __shared__ u16 VT[2][64 * 128];

  const int tid = threadIdx.x;
  const int lane = tid & 63, wave = tid >> 6;
  const int quad = lane >> 4, l16 = lane & 15;
  const int qtA = blockIdx.x, qtB = 7 - blockIdx.x;
  const int h = blockIdx.y, b = blockIdx.z, kvh = h >> 2;
  const size_t tokBase = (size_t)b * 1024;
  const int qcol = h * 64, kcol = 2048 + kvh * 64;
  const int srow = tid >> 3, spc = tid & 7, ssc = spc ^ (srow & 7);

  auto stageK = [&](const u16* gbase, u16* L) {   // natural 128x64, swizzled chunks
#pragma unroll
    for (int i = 0; i < 4; i++)
      ld16_lds(gbase + (size_t)(srow + i * 32) * 3072 + ssc * 8, &L[tid * 8 + i * 2048]);
  };
  const u16* vimg = vkt + (((size_t)b * 8 + kvh) << 16);
  auto stageV = [&](int kt, u16* L) {             // pre-swizzled image: linear copy
    const u16* g = vimg + ((size_t)kt << 13);
#pragma unroll
    for (int i = 0; i < 4; i++)
      ld16_lds(g + i * 2048 + tid * 8, &L[tid * 8 + i * 2048]);
  };

  // ---- stage both Q tiles into the K buffers, extract fragments ----
  stageK(qkv + (tokBase + qtA * 128) * 3072 + qcol, Ks[0]);
  stageK(qkv + (tokBase + qtB * 128) * 3072 + qcol, Ks[1]);
  __syncthreads();
  bf16x8 qfA[2][2], qfB[2][2];   // B-frag: n=q=l16, kdim=d contiguous
#pragma unroll
  for (int nq = 0; nq < 2; nq++) {
    int qrow = wave * 32 + nq * 16 + l16;
#pragma unroll
    for (int ks = 0; ks < 2; ks++) {
      int c = (ks * 4 + quad) ^ (qrow & 7);
      qfA[nq][ks] = *(const bf16x8*)&Ks[0][qrow * 64 + c * 8];
      qfB[nq][ks] = *(const bf16x8*)&Ks[1][qrow * 64 + c * 8];
    }
  }
  __syncthreads();   // Q reads done before K DMA overwrites

  float lA[2] = {0.f, 0.f}, lB[2] = {0.f, 0.f};
  f32x4 oA[4][2] = {}, oB[4][2] = {};   // O^T: d=md*16+quad*4+r, q=nq*16+l16

  auto proc = [&](const bf16x8 (&kf)[2][2], const bf16x8 (&va)[4], const bf16x8 (&qf)[2][2],
                  f32x4 (&o)[4][2], float (&lacc)[2], bool msk, int c) {
    f32x4 s[2][2] = {};   // [nq][mkl]: k = (c*2+mkl)*16 + quad*4 + r, q = nq*16+l16
    __builtin_amdgcn_s_setprio(1);
#pragma unroll
    for (int mkl = 0; mkl < 2; mkl++)
#pragma unroll
      for (int ks = 0; ks < 2; ks++) {
        s[0][mkl] = __builtin_amdgcn_mfma_f32_16x16x32_bf16(kf[mkl][ks], qf[0][ks], s[0][mkl], 0, 0, 0);
        s[1][mkl] = __builtin_amdgcn_mfma_f32_16x16x32_bf16(kf[mkl][ks], qf[1][ks], s[1][mkl], 0, 0, 0);
      }
    __builtin_amdgcn_s_setprio(0);
    if (msk) {
#pragma unroll
      for (int nq = 0; nq < 2; nq++) {
        int q = wave * 32 + nq * 16 + l16;
#pragma unroll
        for (int mkl = 0; mkl < 2; mkl++)
#pragma unroll
          for (int r = 0; r < 4; r++)
            if ((c * 2 + mkl) * 16 + quad * 4 + r > q) s[nq][mkl][r] = -3e38f;
      }
    }
    bf16x8 pf[2];
#pragma unroll
    for (int nq = 0; nq < 2; nq++) {
      float a0 = 0.f;
#pragma unroll
      for (int mkl = 0; mkl < 2; mkl++)
#pragma unroll
        for (int r = 0; r < 4; r++) {
          float p = __builtin_amdgcn_exp2f(s[nq][mkl][r]);
          s[nq][mkl][r] = p;
          a0 += p;
        }
      lacc[nq] += a0;
      pf[nq][0] = (__bf16)s[nq][0][0]; pf[nq][1] = (__bf16)s[nq][0][1];
      pf[nq][2] = (__bf16)s[nq][0][2]; pf[nq][3] = (__bf16)s[nq][0][3];
      pf[nq][4] = (__bf16)s[nq][1][0]; pf[nq][5] = (__bf16)s[nq][1][1];
      pf[nq][6] = (__bf16)s[nq][1][2]; pf[nq][7] = (__bf16)s[nq][1][3];
    }
    __builtin_amdgcn_s_setprio(1);
#pragma unroll
    for (int md = 0; md < 4; md++) {
      o[md][0] = __builtin_amdgcn_mfma_f32_16x16x32_bf16(va[md], pf[0], o[md][0], 0, 0, 0);
      o[md][1] = __builtin_amdgcn_mfma_f32_16x16x32_bf16(va[md], pf[1], o[md][1], 0, 0, 0);
    }
    __builtin_amdgcn_s_setprio(0);
  };

  // ---- main loop: double-buffered K + VT DMA, one barrier per iteration ----
  stageK(qkv + tokBase * 3072 + kcol, Ks[0]);
  stageV(0, VT[0]);

  for (int kt = 0; kt <= qtB; kt++) {
    const int cur = kt & 1;
    __syncthreads();   // drains DMA for kt; all waves done with bufs[1-cur]
    if (kt < qtB) {
      stageK(qkv + (tokBase + (kt + 1) * 128) * 3072 + kcol, Ks[1 - cur]);
      stageV(kt + 1, VT[1 - cur]);
    }
    const bool doA = (kt <= qtA), mA = (kt == qtA), mB = (kt == qtB);
    const u16* K = Ks[cur];
    const u16* V = VT[cur];
#pragma unroll
    for (int c = 0; c < 4; c++) {
      bf16x8 kf[2][2];   // A-frag: m=krow=mk*16+l16, kdim=d
#pragma unroll
      for (int mkl = 0; mkl < 2; mkl++) {
        int krow = (c * 2 + mkl) * 16 + l16;
#pragma unroll
        for (int ks = 0; ks < 2; ks++)
          kf[mkl][ks] = *(const bf16x8*)&K[krow * 64 + ((ks * 4 + quad) ^ (krow & 7)) * 8];
      }
      bf16x8 va[4];      // A-frag V^T: m=d=md*16+l16, k-chunk c
#pragma unroll
      for (int md = 0; md < 4; md++) {
        int dd = md * 16 + l16;
        va[md] = *(const bf16x8*)&V[dd * 128 + ((c * 4 + quad) ^ l16) * 8];
      }
      proc(kf, va, qfB, oB, lB, mB, c);
      if (doA) proc(kf, va, qfA, oA, lA, mA, c);
    }
  }

  // ---- epilogue: reduce l across quads (2 shfls), O/l, b64 stores ----
  auto epilogue = [&](const f32x4 (&o)[4][2], const float (&lacc)[2], int qt_tile) {
#pragma unroll
    for (int nq = 0; nq < 2; nq++) {
      float l = lacc[nq];
      l += __shfl_xor(l, 16);
      l += __shfl_xor(l, 32);
      float inv = 1.0f / l;
      int t = qt_tile * 128 + wave * 32 + nq * 16 + l16;
      size_t rowOff = (tokBase + t) * 2048 + qcol;
#pragma unroll
      for (int md = 0; md < 4; md++) {
        bf16x4 w;
        w[0] = (__bf16)(o[md][nq][0] * inv);
        w[1] = (__bf16)(o[md][nq][1] * inv);
        w[2] = (__bf16)(o[md][nq][2] * inv);
        w[3] = (__bf16)(o[md][nq][3] * inv);
        *(bf16x4*)&attn[rowOff + md * 16 + quad * 4] = w;
      }
    }
  };
  epilogue(oB, lB, qtB);
  epilogue(oA, lA, qtA);
}

// ---------------- launch ----------------
extern "C" void kernel_launch(void* const* d_in, const int* in_sizes, int n_in,
                              void* d_out, int out_size, void* d_ws, size_t ws_size,
                              hipStream_t stream) {
  const float* hs = (const float*)d_in[0];
  const float* cs = (const float*)d_in[1];
  const float* sn = (const float*)d_in[2];
  const float* Wq = (const float*)d_in[3];
  const float* Wk = (const float*)d_in[4];
  const float* Wv = (const float*)d_in[5];
  const float* Wo = (const float*)d_in[6];
  float* out = (float*)d_out;

  char* ws = (char*)d_ws;
  u16* hsB   = (u16*)(ws);                  // 4096x2048 bf16 (dead after qkv GEMM)
  u16* vkt   = (u16*)(ws);                  // 4MB VkT images, built after qkv GEMM
  u16* wqkvT = (u16*)(ws + 16777216);       // 3072x2048 bf16 [WqT;WkT;WvT]
  u16* woT   = (u16*)(ws + 29360128);       // 2048x2048 bf16
  u16* qkv   = (u16*)(ws + 37748736);       // 4096x3072 bf16
  u16* attnB = (u16*)(ws + 62914560);       // 4096x2048 bf16

  // attention scale folded into Wq: 1/8 * log2(e)  (rope commutes with the scale)
  const float QSCALE = 0.18033688011112042f;

  // fused prep: convert (8192 blocks) + Wq (4096) + Wk (1024) + Wv (1024) + Wo (4096)
  prep<<<18432, 256, 0, stream>>>(hs, hsB, Wq, Wk, Wv, Wo, wqkvT, woT, QSCALE);

  // QKV: 128x192 tile, merged single-phase pipeline, grid 16x32 = 512 = 2/CU.
  gemm5<u16, 192><<<dim3(16, 32), 256, 0, stream>>>(hsB, wqkvT, qkv, 4096, 3072, 2048);
  // RoPE Q+K in-place + V images.
  rope_vkt<<<dim3(8, 32, 4), 256, 0, stream>>>(qkv, vkt, cs, sn);
  flash_attn<<<dim3(4, 32, 4), 256, 0, stream>>>(qkv, vkt, attnB);
  // Wo: 128x128 tile, grid 16x32 = 512 = 2/CU.
  gemm5<float, 128><<<dim3(16, 32), 256, 0, stream>>>(attnB, woT, out, 4096, 2048, 2048);
}

// Round 10
// 250.295 us; speedup vs baseline: 2.0560x; 1.0375x over previous
//
#include <hip/hip_runtime.h>
#include <type_traits>

// Problem constants (ExaoneFlashAttention): B=4, S=1024, T=4096, D_MODEL=2048,
// H=32, KVH=8, HD=64, GROUPS=4, SCALE=1/8. All bf16 MFMA, f32 accum.
// Attention scale * log2(e) folded into Wq transpose -> softmax in exp2 domain.
// Max-free softmax (logits bounded). RoPE applied by rope_vkt pre-pass (in-place
// on qkv; QK^T invariant under common d-relabeling, rope commutes with Q scale).

typedef __bf16 bf16x8 __attribute__((ext_vector_type(8)));
typedef __bf16 bf16x4 __attribute__((ext_vector_type(4)));
typedef float f32x4 __attribute__((ext_vector_type(4)));
typedef unsigned short u16;
typedef unsigned int u32;

#define DEVI __device__ __forceinline__

DEVI u16 f2bf(float f) {           // RNE f32->bf16 (finite inputs)
  u32 u = __builtin_bit_cast(u32, f);
  u += 0x7FFF + ((u >> 16) & 1);
  return (u16)(u >> 16);
}

// async global->LDS, 16B per lane. LDS dest must be wave-uniform base + lane*16.
DEVI void ld16_lds(const void* g, void* l) {
  __builtin_amdgcn_global_load_lds((const __attribute__((address_space(1))) u32*)g,
                                   (__attribute__((address_space(3))) u32*)l, 16, 0, 0);
}

template <int N> DEVI void waitvm() {   // counted vmcnt (T4)
  if constexpr (N == 0) asm volatile("s_waitcnt vmcnt(0)" ::: "memory");
  else if constexpr (N == 8) asm volatile("s_waitcnt vmcnt(8)" ::: "memory");
  else if constexpr (N == 10) asm volatile("s_waitcnt vmcnt(10)" ::: "memory");
  else static_assert(N == 0, "unsupported vmcnt");
}
template <int N> DEVI void lgkmN() {   // counted DS wait (in-order retire)
  if constexpr (N == 0) asm volatile("s_waitcnt lgkmcnt(0)" ::: "memory");
  else if constexpr (N == 4) asm volatile("s_waitcnt lgkmcnt(4)" ::: "memory");
  else if constexpr (N == 6) asm volatile("s_waitcnt lgkmcnt(6)" ::: "memory");
  else static_assert(N == 0, "unsupported lgkmcnt");
  __builtin_amdgcn_sched_barrier(0);   // rule #18
}
DEVI void barrier() { __builtin_amdgcn_s_barrier(); }

// ---------------- fused prep: f32->bf16 convert + 4 weight transposes -------------------
__global__ __launch_bounds__(256) void prep(const float* __restrict__ hs, u16* __restrict__ hsB,
                                            const float* __restrict__ Wq, const float* __restrict__ Wk,
                                            const float* __restrict__ Wv, const float* __restrict__ Wo,
                                            u16* __restrict__ wqkvT, u16* __restrict__ woT,
                                            float qscale) {
  int b = blockIdx.x;
  if (b < 8192) {                      // ---- convert hs (4096x2048 f32) -> hsB bf16 ----
    int i = b * 256 + threadIdx.x;
    float4 v = ((const float4*)hs)[i];
    ushort4 o;
    o.x = f2bf(v.x); o.y = f2bf(v.y); o.z = f2bf(v.z); o.w = f2bf(v.w);
    ((ushort4*)hsB)[i] = o;
    return;
  }
  b -= 8192;
  const float* src; u16* dst; int R, C, bx, by; float sc = 1.0f;
  if (b < 4096)      { src = Wq; dst = wqkvT;                         R = 2048; C = 2048; bx = b & 63; by = b >> 6; sc = qscale; }
  else if (b < 5120) { b -= 4096; src = Wk; dst = wqkvT + (size_t)2048 * 2048; R = 2048; C = 512; bx = b & 15; by = b >> 4; }
  else if (b < 6144) { b -= 5120; src = Wv; dst = wqkvT + (size_t)2560 * 2048; R = 2048; C = 512; bx = b & 15; by = b >> 4; }
  else               { b -= 6144; src = Wo; dst = woT;                R = 2048; C = 2048; bx = b & 63; by = b >> 6; }
  __shared__ float tile[32][33];
  int c0 = bx * 32, r0 = by * 32;
  int tx = threadIdx.x & 31, ty = threadIdx.x >> 5;   // ty 0..7
#pragma unroll
  for (int i = 0; i < 32; i += 8)
    tile[ty + i][tx] = src[(size_t)(r0 + ty + i) * C + (c0 + tx)];
  __syncthreads();
#pragma unroll
  for (int i = 0; i < 32; i += 8)
    dst[(size_t)(c0 + ty + i) * R + (r0 + tx)] = f2bf(tile[tx][ty + i] * sc);
}

// ---------------- GEMM v10: merged read-phase + 2-tiles-ahead counted-vmcnt -------------
// C(MxN) = A(MxK) * BT(NxK)^T, bf16 in, f32 acc. BM=128 x BN (192 QKV / 128 Wo),
// BK=64, 256 thr = 4 waves (2M x 2N), wave tile 64 x BN/2 (interleaved halves).
// LDS 80/64 KB -> 2 blocks/CU. r9 lesson: stage(t+1) drained at the SAME
// iteration's end had only ~500cy cover vs ~900cy HBM -> vmcnt stall dominated
// (per-block-tile wall ~1900cy vs 230cy MFMA). v10 merges r9's single read-phase
// with r6's two-ahead staging:
//   iter t (buf=t&1):
//     ldB0 ; SB ; ldA ; SB ; ldB1       (20/16 ds_reads, group order pinned so
//                                        counted lgkm is safe)
//     lgkm(2NH) ; mm0 (b1 drains under) ; lgkm(0)
//     barrier                           (all waves done reading buf)
//     stage(t+2) -> buf                 (tile t dead; full-iter+ cover ~1300cy)
//     mm1
//     waitvm<VMW>                       (drains tile t+1, issued LAST iter;
//                                        leaves t+2's VMW flying — never 0)
//     barrier                           (publish buf^1 for next iter)
// vmcnt ledger: steady outstanding 2*VMW -> wait VMW drains exactly t+1.
// Prologue stages tiles 0+1, waits VMW (tile1 keeps flying). Tail: when t+2>=NT
// nothing staged -> waitvm<0>. Register footprint = r9 (af 32 + b0/b1 48,
// ~108 VGPR, no spill — r7/r8 lesson: no extra prefetch arrays).
// T2 chunk swizzle: LDS[row][ch] = global chunk ch^(row&7) via pre-swizzled
// source, same XOR on read -> conflict-free ds_read_b128 (0 conflicts measured).
// T1 XCD swizzle: nwg=512 %8==0.
template <typename OutT, int BN>
__global__ __launch_bounds__(256, 2) void gemm6(const u16* __restrict__ A,
                                                const u16* __restrict__ BT,
                                                OutT* __restrict__ C, int M, int N, int K) {
  constexpr int NF = BN / 32;         // n-frags per wave: 6 (192) / 4 (128)
  constexpr int NH = NF / 2;          // frags per n-half: 3 / 2
  constexpr int HW = BN / 2;          // B half rows: 96 / 64
  constexpr int SW = HW / 2;          // per-wave span within a half: 48 / 32
  constexpr int LB0 = BN / 64;        // B-half stage loads/thr: 3 / 2
  constexpr int VMW = 4 + 2 * LB0;    // loads per full-tile stage: 10 / 8
  __shared__ u16 As[2][128 * 64];
  __shared__ u16 Bs[2][BN * 64];
  const int tid = threadIdx.x;
  const int lane = tid & 63, wave = tid >> 6;
  const int quad = lane >> 4, l16 = lane & 15;

  // ---- XCD-aware block swizzle (bijective: nwg = 512, %8 == 0) ----
  const int nwg = gridDim.x * gridDim.y;
  const int bid = blockIdx.y * gridDim.x + blockIdx.x;
  const int swz = (bid & 7) * (nwg >> 3) + (bid >> 3);
  const int m0 = (swz / gridDim.x) * 128, n0 = (swz % gridDim.x) * BN;
  const int wr = wave >> 1, wc = wave & 1;   // 2M x 2N wave grid

  f32x4 acc[4][NF] = {};

  // ---- stage one full K-tile t into explicit buffers (A: 4 loads/thr, B: 2*LB0) ----
  auto stage = [&](int t, u16* Ad, u16* Bd) {
    {
      const u16* G = A + (size_t)m0 * K + t * 64;
#pragma unroll
      for (int i = 0; i < 4; ++i) {
        int id = i * 256 + tid, row = id >> 3, ch = id & 7;
        ld16_lds(G + (size_t)row * K + (ch ^ (row & 7)) * 8, Ad + id * 8);
      }
    }
#pragma unroll
    for (int h = 0; h < 2; ++h) {
      const u16* G = BT + (size_t)(n0 + h * HW) * K + t * 64;
#pragma unroll
      for (int i = 0; i < LB0; ++i) {
        int id = i * 256 + tid, row = id >> 3, ch = id & 7;
        // h*HW multiple of 8 -> (local row & 7) == (global row & 7)
        ld16_lds(G + (size_t)row * K + (ch ^ (row & 7)) * 8, Bd + (h * HW * 64) + id * 8);
      }
    }
  };

  // ---- register fragments: single sets (r9 footprint; fits, no spill) ----
  bf16x8 af[4][2], b0[NH][2], b1[NH][2];
  auto ldAF = [&](const u16* Ab) {
#pragma unroll
    for (int i = 0; i < 4; ++i)
#pragma unroll
      for (int ks = 0; ks < 2; ++ks) {
        int r = wr * 64 + i * 16 + l16;
        af[i][ks] = *(const bf16x8*)&Ab[r * 64 + (((ks * 4 + quad) ^ (r & 7)) * 8)];
      }
  };
  auto ldB = [&](bf16x8 (&bv)[NH][2], int half, const u16* Bb) {
#pragma unroll
    for (int j = 0; j < NH; ++j)
#pragma unroll
      for (int ks = 0; ks < 2; ++ks) {
        int rb = half * HW + wc * SW + j * 16 + l16;
        bv[j][ks] = *(const bf16x8*)&Bb[rb * 64 + (((ks * 4 + quad) ^ (rb & 7)) * 8)];
      }
  };
  auto mmh = [&](const bf16x8 (&bv)[NH][2], int jo) {   // 4 x NH x 2 MFMA (T5 wrap)
    __builtin_amdgcn_s_setprio(1);
#pragma unroll
    for (int i = 0; i < 4; ++i)
#pragma unroll
      for (int j = 0; j < NH; ++j)
#pragma unroll
        for (int ks = 0; ks < 2; ++ks)
          acc[i][jo + j] =
              __builtin_amdgcn_mfma_f32_16x16x32_bf16(af[i][ks], bv[j][ks], acc[i][jo + j], 0, 0, 0);
    __builtin_amdgcn_s_setprio(0);
  };

  const int NT = K / 64;   // 32 for both GEMMs

  // ---- prologue: stage tiles 0 AND 1; drain tile0 (tile1's VMW stay flying) ----
  stage(0, As[0], Bs[0]);
  stage(1, As[1], Bs[1]);
  waitvm<VMW>();
  barrier();

#pragma unroll 2
  for (int t = 0; t < NT; ++t) {
    const int buf = t & 1;
    // issue all tile-t frag reads, group order pinned (b0, A, b1)
    ldB(b0, 0, Bs[buf]);
    __builtin_amdgcn_sched_barrier(0);
    ldAF(As[buf]);
    __builtin_amdgcn_sched_barrier(0);
    ldB(b1, 1, Bs[buf]);
    lgkmN<2 * NH>();          // b0 + A complete; b1 flying under mm0
    mmh(b0, 0);
    lgkmN<0>();               // b1 complete — buf fully read by this wave
    barrier();                // ...and by ALL waves: buf restage now safe
    if (t + 2 < NT) stage(t + 2, As[buf], Bs[buf]);   // ~1300cy cover to its wait
    mmh(b1, NH);
    if (t + 1 < NT) {
      if (t + 2 < NT) waitvm<VMW>();   // drain tile t+1 (issued last iter); t+2 flies
      else waitvm<0>();                // tail: nothing new staged
      barrier();                       // publish buf^1 for next iteration
    }
  }

  // ---- epilogue: C/D layout col=lane&15, row=quad*4+r ----
#pragma unroll
  for (int i = 0; i < 4; ++i) {
    int row = m0 + wr * 64 + i * 16 + quad * 4;
#pragma unroll
    for (int j = 0; j < NF; ++j) {
      int half = j / NH, jj = j % NH;
      int col = n0 + half * HW + wc * SW + jj * 16 + l16;
#pragma unroll
      for (int r = 0; r < 4; ++r) {
        size_t off = (size_t)(row + r) * N + col;
        if constexpr (sizeof(OutT) == 2) C[off] = f2bf(acc[i][j][r]);
        else C[off] = acc[i][j][r];
      }
    }
  }
}

// ---------------- rope_vkt: RoPE Q/K in-place + V tile images ---------------------------
// Grid (8 kt, 32 h, 4 b). Every block ropes the Q tile [128 tok x 64] of head h.
// Blocks with h<8 additionally rope the K tile of kvh=h and build the V image
// (transposed, chunk-swizzled, k-permuted). RoPE pair (d, d+32) is in-row ->
// one thread owns a full pair group; cs/sn indexed by global token.
__global__ __launch_bounds__(256) void rope_vkt(u16* __restrict__ qkv,
                                                u16* __restrict__ vkt,
                                                const float* __restrict__ cs,
                                                const float* __restrict__ sn) {
  const int kt = blockIdx.x, h = blockIdx.y, b = blockIdx.z;
  const int tid = threadIdx.x;
  const size_t tok0 = (size_t)b * 1024 + (size_t)kt * 128;

  // ---- RoPE: 2 threads per row, 2 pair-groups (8 pairs each) per thread ----
  {
    const int r = tid >> 1, hf = tid & 1;
    const size_t t = tok0 + r;
    const float* cr = cs + t * 32;
    const float* sr = sn + t * 32;
    u16* qrow = qkv + t * 3072 + h * 64;
    u16* krow = qkv + t * 3072 + 2048 + h * 64;   // used only when h<8
#pragma unroll
    for (int gg = 0; gg < 2; ++gg) {
      const int g = hf * 2 + gg;                  // pair-group 0..3 (d = g*8+e)
      float cv[8], sv[8];
#pragma unroll
      for (int e = 0; e < 8; ++e) { cv[e] = cr[g * 8 + e]; sv[e] = sr[g * 8 + e]; }
      {
        bf16x8 a = *(bf16x8*)&qrow[g * 8];
        bf16x8 b2 = *(bf16x8*)&qrow[g * 8 + 32];
#pragma unroll
        for (int e = 0; e < 8; ++e) {
          float x1 = (float)a[e], x2 = (float)b2[e];
          a[e] = (__bf16)(x1 * cv[e] - x2 * sv[e]);
          b2[e] = (__bf16)(x2 * cv[e] + x1 * sv[e]);
        }
        *(bf16x8*)&qrow[g * 8] = a;
        *(bf16x8*)&qrow[g * 8 + 32] = b2;
      }
      if (h < 8) {
        bf16x8 a = *(bf16x8*)&krow[g * 8];
        bf16x8 b2 = *(bf16x8*)&krow[g * 8 + 32];
#pragma unroll
        for (int e = 0; e < 8; ++e) {
          float x1 = (float)a[e], x2 = (float)b2[e];
          a[e] = (__bf16)(x1 * cv[e] - x2 * sv[e]);
          b2[e] = (__bf16)(x2 * cv[e] + x1 * sv[e]);
        }
        *(bf16x8*)&krow[g * 8] = a;
        *(bf16x8*)&krow[g * 8 + 32] = b2;
      }
    }
  }
  if (h >= 8) return;

  // ---- V image build (kvh = h) ----
  __shared__ u16 Vn[128 * 64];
  const u16* src = qkv + tok0 * 3072 + 2560 + h * 64;
  {
    int tok = tid >> 1, hf = tid & 1;
    const uint4* s4 = (const uint4*)(src + (size_t)tok * 3072 + hf * 32);
    uint4* d4 = (uint4*)&Vn[tok * 64 + hf * 32];
#pragma unroll
    for (int j = 0; j < 4; j++) d4[j] = s4[j];
  }
  __syncthreads();
  u16* img = vkt + ((((size_t)b * 8 + h) * 8 + kt) << 13);   // 8192 u16 / image
#pragma unroll
  for (int i = 0; i < 4; i++) {
    int c = tid * 4 + i;                 // chunk index 0..1023
    int dd = c >> 4, chsw = c & 15;
    int ch = chsw ^ (dd & 15);
    u16 tmp[8];
#pragma unroll
    for (int p = 0; p < 8; p++) {
      int col = ch * 8 + p;
      int g = col >> 5, kl = col & 31;
      int kph = ((kl >> 2) & 1) * 16 + ((kl >> 4) & 1) * 8 + ((kl >> 3) & 1) * 4 + (kl & 3);
      tmp[p] = Vn[(g * 32 + kph) * 64 + dd];
    }
    *(uint4*)&img[c * 8] = *(const uint4*)tmp;
  }
}

// ---------------- flash attention v4 ----------------
// Grid (4, 32, 4) = 512 blocks = 2/CU. Two q-tiles per block (qtA=bx, qtB=7-bx):
// 9 tile-steps per block, K/V staged once for both. Transposed-score form,
// max-free exp2 softmax, P kept in registers via the k-permutation baked into
// the VkT images. K and VT double-buffered pure DMA. One barrier/iter.
// LDS: Ks 2x16KB + VT 2x16KB = 64KB -> 2 blocks/CU. T5 setprio on MFMA clusters.
__global__ __launch_bounds__(256, 2) void flash_attn(const u16* __restrict__ qkv,
                                                     const u16* __restrict__ vkt,
                                                     u16* __restrict__ attn) {
  __shared__ u16 Ks[2][128 * 64];
  __shared__ u16 VT[2][64 * 128];

  const int tid = threadIdx.x;
  const int lane = tid & 63, wave = tid >> 6;
  const int quad = lane >> 4, l16 = lane & 15;
  const int qtA = blockIdx.x, qtB = 7 - blockIdx.x;
  const int h = blockIdx.y, b = blockIdx.z, kvh = h >> 2;
  const size_t tokBase = (size_t)b * 1024;
  const int qcol = h * 64, kcol = 2048 + kvh * 64;
  const int srow = tid >> 3, spc = tid & 7, ssc = spc ^ (srow & 7);

  auto stageK = [&](const u16* gbase, u16* L) {   // natural 128x64, swizzled chunks
#pragma unroll
    for (int i = 0; i < 4; i++)
      ld16_lds(gbase + (size_t)(srow + i * 32) * 3072 + ssc * 8, &L[tid * 8 + i * 2048]);
  };
  const u16* vimg = vkt + (((size_t)b * 8 + kvh) << 16);
  auto stageV = [&](int kt, u16* L) {             // pre-swizzled image: linear copy
    const u16* g = vimg + ((size_t)kt << 13);
#pragma unroll
    for (int i = 0; i < 4; i++)
      ld16_lds(g + i * 2048 + tid * 8, &L[tid * 8 + i * 2048]);
  };

  // ---- stage both Q tiles into the K buffers, extract fragments ----
  stageK(qkv + (tokBase + qtA * 128) * 3072 + qcol, Ks[0]);
  stageK(qkv + (tokBase + qtB * 128) * 3072 + qcol, Ks[1]);
  __syncthreads();
  bf16x8 qfA[2][2], qfB[2][2];   // B-frag: n=q=l16, kdim=d contiguous
#pragma unroll
  for (int nq = 0; nq < 2; nq++) {
    int qrow = wave * 32 + nq * 16 + l16;
#pragma unroll
    for (int ks = 0; ks < 2; ks++) {
      int c = (ks * 4 + quad) ^ (qrow & 7);
      qfA[nq][ks] = *(const bf16x8*)&Ks[0][qrow * 64 + c * 8];
      qfB[nq][ks] = *(const bf16x8*)&Ks[1][qrow * 64 + c * 8];
    }
  }
  __syncthreads();   // Q reads done before K DMA overwrites

  float lA[2] = {0.f, 0.f}, lB[2] = {0.f, 0.f};
  f32x4 oA[4][2] = {}, oB[4][2] = {};   // O^T: d=md*16+quad*4+r, q=nq*16+l16

  auto proc = [&](const bf16x8 (&kf)[2][2], const bf16x8 (&va)[4], const bf16x8 (&qf)[2][2],
                  f32x4 (&o)[4][2], float (&lacc)[2], bool msk, int c) {
    f32x4 s[2][2] = {};   // [nq][mkl]: k = (c*2+mkl)*16 + quad*4 + r, q = nq*16+l16
    __builtin_amdgcn_s_setprio(1);
#pragma unroll
    for (int mkl = 0; mkl < 2; mkl++)
#pragma unroll
      for (int ks = 0; ks < 2; ks++) {
        s[0][mkl] = __builtin_amdgcn_mfma_f32_16x16x32_bf16(kf[mkl][ks], qf[0][ks], s[0][mkl], 0, 0, 0);
        s[1][mkl] = __builtin_amdgcn_mfma_f32_16x16x32_bf16(kf[mkl][ks], qf[1][ks], s[1][mkl], 0, 0, 0);
      }
    __builtin_amdgcn_s_setprio(0);
    if (msk) {
#pragma unroll
      for (int nq = 0; nq < 2; nq++) {
        int q = wave * 32 + nq * 16 + l16;
#pragma unroll
        for (int mkl = 0; mkl < 2; mkl++)
#pragma unroll
          for (int r = 0; r < 4; r++)
            if ((c * 2 + mkl) * 16 + quad * 4 + r > q) s[nq][mkl][r] = -3e38f;
      }
    }
    bf16x8 pf[2];
#pragma unroll
    for (int nq = 0; nq < 2; nq++) {
      float a0 = 0.f;
#pragma unroll
      for (int mkl = 0; mkl < 2; mkl++)
#pragma unroll
        for (int r = 0; r < 4; r++) {
          float p = __builtin_amdgcn_exp2f(s[nq][mkl][r]);
          s[nq][mkl][r] = p;
          a0 += p;
        }
      lacc[nq] += a0;
      pf[nq][0] = (__bf16)s[nq][0][0]; pf[nq][1] = (__bf16)s[nq][0][1];
      pf[nq][2] = (__bf16)s[nq][0][2]; pf[nq][3] = (__bf16)s[nq][0][3];
      pf[nq][4] = (__bf16)s[nq][1][0]; pf[nq][5] = (__bf16)s[nq][1][1];
      pf[nq][6] = (__bf16)s[nq][1][2]; pf[nq][7] = (__bf16)s[nq][1][3];
    }
    __builtin_amdgcn_s_setprio(1);
#pragma unroll
    for (int md = 0; md < 4; md++) {
      o[md][0] = __builtin_amdgcn_mfma_f32_16x16x32_bf16(va[md], pf[0], o[md][0], 0, 0, 0);
      o[md][1] = __builtin_amdgcn_mfma_f32_16x16x32_bf16(va[md], pf[1], o[md][1], 0, 0, 0);
    }
    __builtin_amdgcn_s_setprio(0);
  };

  // ---- main loop: double-buffered K + VT DMA, one barrier per iteration ----
  stageK(qkv + tokBase * 3072 + kcol, Ks[0]);
  stageV(0, VT[0]);

  for (int kt = 0; kt <= qtB; kt++) {
    const int cur = kt & 1;
    __syncthreads();   // drains DMA for kt; all waves done with bufs[1-cur]
    if (kt < qtB) {
      stageK(qkv + (tokBase + (kt + 1) * 128) * 3072 + kcol, Ks[1 - cur]);
      stageV(kt + 1, VT[1 - cur]);
    }
    const bool doA = (kt <= qtA), mA = (kt == qtA), mB = (kt == qtB);
    const u16* K = Ks[cur];
    const u16* V = VT[cur];
#pragma unroll
    for (int c = 0; c < 4; c++) {
      bf16x8 kf[2][2];   // A-frag: m=krow=mk*16+l16, kdim=d
#pragma unroll
      for (int mkl = 0; mkl < 2; mkl++) {
        int krow = (c * 2 + mkl) * 16 + l16;
#pragma unroll
        for (int ks = 0; ks < 2; ks++)
          kf[mkl][ks] = *(const bf16x8*)&K[krow * 64 + ((ks * 4 + quad) ^ (krow & 7)) * 8];
      }
      bf16x8 va[4];      // A-frag V^T: m=d=md*16+l16, k-chunk c
#pragma unroll
      for (int md = 0; md < 4; md++) {
        int dd = md * 16 + l16;
        va[md] = *(const bf16x8*)&V[dd * 128 + ((c * 4 + quad) ^ l16) * 8];
      }
      proc(kf, va, qfB, oB, lB, mB, c);
      if (doA) proc(kf, va, qfA, oA, lA, mA, c);
    }
  }

  // ---- epilogue: reduce l across quads (2 shfls), O/l, b64 stores ----
  auto epilogue = [&](const f32x4 (&o)[4][2], const float (&lacc)[2], int qt_tile) {
#pragma unroll
    for (int nq = 0; nq < 2; nq++) {
      float l = lacc[nq];
      l += __shfl_xor(l, 16);
      l += __shfl_xor(l, 32);
      float inv = 1.0f / l;
      int t = qt_tile * 128 + wave * 32 + nq * 16 + l16;
      size_t rowOff = (tokBase + t) * 2048 + qcol;
#pragma unroll
      for (int md = 0; md < 4; md++) {
        bf16x4 w;
        w[0] = (__bf16)(o[md][nq][0] * inv);
        w[1] = (__bf16)(o[md][nq][1] * inv);
        w[2] = (__bf16)(o[md][nq][2] * inv);
        w[3] = (__bf16)(o[md][nq][3] * inv);
        *(bf16x4*)&attn[rowOff + md * 16 + quad * 4] = w;
      }
    }
  };
  epilogue(oB, lB, qtB);
  epilogue(oA, lA, qtA);
}

// ---------------- launch ----------------
extern "C" void kernel_launch(void* const* d_in, const int* in_sizes, int n_in,
                              void* d_out, int out_size, void* d_ws, size_t ws_size,
                              hipStream_t stream) {
  const float* hs = (const float*)d_in[0];
  const float* cs = (const float*)d_in[1];
  const float* sn = (const float*)d_in[2];
  const float* Wq = (const float*)d_in[3];
  const float* Wk = (const float*)d_in[4];
  const float* Wv = (const float*)d_in[5];
  const float* Wo = (const float*)d_in[6];
  float* out = (float*)d_out;

  char* ws = (char*)d_ws;
  u16* hsB   = (u16*)(ws);                  // 4096x2048 bf16 (dead after qkv GEMM)
  u16* vkt   = (u16*)(ws);                  // 4MB VkT images, built after qkv GEMM
  u16* wqkvT = (u16*)(ws + 16777216);       // 3072x2048 bf16 [WqT;WkT;WvT]
  u16* woT   = (u16*)(ws + 29360128);       // 2048x2048 bf16
  u16* qkv   = (u16*)(ws + 37748736);       // 4096x3072 bf16
  u16* attnB = (u16*)(ws + 62914560);       // 4096x2048 bf16

  // attention scale folded into Wq: 1/8 * log2(e)  (rope commutes with the scale)
  const float QSCALE = 0.18033688011112042f;

  // fused prep: convert (8192 blocks) + Wq (4096) + Wk (1024) + Wv (1024) + Wo (4096)
  prep<<<18432, 256, 0, stream>>>(hs, hsB, Wq, Wk, Wv, Wo, wqkvT, woT, QSCALE);

  // QKV: 128x192 tile, 2-ahead counted-vmcnt pipeline, grid 16x32 = 512 = 2/CU.
  gemm6<u16, 192><<<dim3(16, 32), 256, 0, stream>>>(hsB, wqkvT, qkv, 4096, 3072, 2048);
  // RoPE Q+K in-place + V images.
  rope_vkt<<<dim3(8, 32, 4), 256, 0, stream>>>(qkv, vkt, cs, sn);
  flash_attn<<<dim3(4, 32, 4), 256, 0, stream>>>(qkv, vkt, attnB);
  // Wo: 128x128 tile, grid 16x32 = 512 = 2/CU.
  gemm6<float, 128><<<dim3(16, 32), 256, 0, stream>>>(attnB, woT, out, 4096, 2048, 2048);
}

// Round 11
// 236.381 us; speedup vs baseline: 2.1770x; 1.0589x over previous
//
#include <hip/hip_runtime.h>
#include <type_traits>

// Problem constants (ExaoneFlashAttention): B=4, S=1024, T=4096, D_MODEL=2048,
// H=32, KVH=8, HD=64, GROUPS=4, SCALE=1/8. All bf16 MFMA, f32 accum.
// Attention scale * log2(e) folded into Wq transpose -> softmax in exp2 domain.
// Max-free softmax (logits bounded). RoPE: K roped by kv_prep (in-place on qkv);
// Q roped INSIDE flash_attn on the staged LDS tiles (one RMW pass per block,
// outside the main loop) — saves the 32MB Q read-modify-write of the old
// rope_vkt pre-pass. QK^T invariant under common d-relabeling; rope commutes
// with the folded Q scale.

typedef __bf16 bf16x8 __attribute__((ext_vector_type(8)));
typedef __bf16 bf16x4 __attribute__((ext_vector_type(4)));
typedef float f32x4 __attribute__((ext_vector_type(4)));
typedef unsigned short u16;
typedef unsigned int u32;

#define DEVI __device__ __forceinline__

DEVI u16 f2bf(float f) {           // RNE f32->bf16 (finite inputs)
  u32 u = __builtin_bit_cast(u32, f);
  u += 0x7FFF + ((u >> 16) & 1);
  return (u16)(u >> 16);
}

// async global->LDS, 16B per lane. LDS dest must be wave-uniform base + lane*16.
DEVI void ld16_lds(const void* g, void* l) {
  __builtin_amdgcn_global_load_lds((const __attribute__((address_space(1))) u32*)g,
                                   (__attribute__((address_space(3))) u32*)l, 16, 0, 0);
}

template <int N> DEVI void waitvm() {   // counted vmcnt (T4)
  if constexpr (N == 0) asm volatile("s_waitcnt vmcnt(0)" ::: "memory");
  else if constexpr (N == 8) asm volatile("s_waitcnt vmcnt(8)" ::: "memory");
  else if constexpr (N == 10) asm volatile("s_waitcnt vmcnt(10)" ::: "memory");
  else static_assert(N == 0, "unsupported vmcnt");
}
template <int N> DEVI void lgkmN() {   // counted DS wait (in-order retire)
  if constexpr (N == 0) asm volatile("s_waitcnt lgkmcnt(0)" ::: "memory");
  else if constexpr (N == 4) asm volatile("s_waitcnt lgkmcnt(4)" ::: "memory");
  else if constexpr (N == 6) asm volatile("s_waitcnt lgkmcnt(6)" ::: "memory");
  else static_assert(N == 0, "unsupported lgkmcnt");
  __builtin_amdgcn_sched_barrier(0);   // rule #18
}
DEVI void barrier() { __builtin_amdgcn_s_barrier(); }

// ---------------- fused prep: f32->bf16 convert + 4 weight transposes -------------------
__global__ __launch_bounds__(256) void prep(const float* __restrict__ hs, u16* __restrict__ hsB,
                                            const float* __restrict__ Wq, const float* __restrict__ Wk,
                                            const float* __restrict__ Wv, const float* __restrict__ Wo,
                                            u16* __restrict__ wqkvT, u16* __restrict__ woT,
                                            float qscale) {
  int b = blockIdx.x;
  if (b < 8192) {                      // ---- convert hs (4096x2048 f32) -> hsB bf16 ----
    int i = b * 256 + threadIdx.x;
    float4 v = ((const float4*)hs)[i];
    ushort4 o;
    o.x = f2bf(v.x); o.y = f2bf(v.y); o.z = f2bf(v.z); o.w = f2bf(v.w);
    ((ushort4*)hsB)[i] = o;
    return;
  }
  b -= 8192;
  const float* src; u16* dst; int R, C, bx, by; float sc = 1.0f;
  if (b < 4096)      { src = Wq; dst = wqkvT;                         R = 2048; C = 2048; bx = b & 63; by = b >> 6; sc = qscale; }
  else if (b < 5120) { b -= 4096; src = Wk; dst = wqkvT + (size_t)2048 * 2048; R = 2048; C = 512; bx = b & 15; by = b >> 4; }
  else if (b < 6144) { b -= 5120; src = Wv; dst = wqkvT + (size_t)2560 * 2048; R = 2048; C = 512; bx = b & 15; by = b >> 4; }
  else               { b -= 6144; src = Wo; dst = woT;                R = 2048; C = 2048; bx = b & 63; by = b >> 6; }
  __shared__ float tile[32][33];
  int c0 = bx * 32, r0 = by * 32;
  int tx = threadIdx.x & 31, ty = threadIdx.x >> 5;   // ty 0..7
#pragma unroll
  for (int i = 0; i < 32; i += 8)
    tile[ty + i][tx] = src[(size_t)(r0 + ty + i) * C + (c0 + tx)];
  __syncthreads();
#pragma unroll
  for (int i = 0; i < 32; i += 8)
    dst[(size_t)(c0 + ty + i) * R + (r0 + tx)] = f2bf(tile[tx][ty + i] * sc);
}

// ---------------- GEMM v10 (unchanged — at structural plateau, r10 post-mortem) ---------
// 50.3us QKV / MfmaUtil 41-45%. Wall model: per block-iter ~3770cy = 1862cy MFMA
// + ~940cy LDS traffic + barrier/lgkm residual. r6/r9/r10 schedule variants all
// land 50-54us; register-prefetch variants (r7/r8) spill. Frozen this round.
template <typename OutT, int BN>
__global__ __launch_bounds__(256, 2) void gemm6(const u16* __restrict__ A,
                                                const u16* __restrict__ BT,
                                                OutT* __restrict__ C, int M, int N, int K) {
  constexpr int NF = BN / 32;         // n-frags per wave: 6 (192) / 4 (128)
  constexpr int NH = NF / 2;          // frags per n-half: 3 / 2
  constexpr int HW = BN / 2;          // B half rows: 96 / 64
  constexpr int SW = HW / 2;          // per-wave span within a half: 48 / 32
  constexpr int LB0 = BN / 64;        // B-half stage loads/thr: 3 / 2
  constexpr int VMW = 4 + 2 * LB0;    // loads per full-tile stage: 10 / 8
  __shared__ u16 As[2][128 * 64];
  __shared__ u16 Bs[2][BN * 64];
  const int tid = threadIdx.x;
  const int lane = tid & 63, wave = tid >> 6;
  const int quad = lane >> 4, l16 = lane & 15;

  // ---- XCD-aware block swizzle (bijective: nwg = 512, %8 == 0) ----
  const int nwg = gridDim.x * gridDim.y;
  const int bid = blockIdx.y * gridDim.x + blockIdx.x;
  const int swz = (bid & 7) * (nwg >> 3) + (bid >> 3);
  const int m0 = (swz / gridDim.x) * 128, n0 = (swz % gridDim.x) * BN;
  const int wr = wave >> 1, wc = wave & 1;   // 2M x 2N wave grid

  f32x4 acc[4][NF] = {};

  // ---- stage one full K-tile t into explicit buffers (A: 4 loads/thr, B: 2*LB0) ----
  auto stage = [&](int t, u16* Ad, u16* Bd) {
    {
      const u16* G = A + (size_t)m0 * K + t * 64;
#pragma unroll
      for (int i = 0; i < 4; ++i) {
        int id = i * 256 + tid, row = id >> 3, ch = id & 7;
        ld16_lds(G + (size_t)row * K + (ch ^ (row & 7)) * 8, Ad + id * 8);
      }
    }
#pragma unroll
    for (int h = 0; h < 2; ++h) {
      const u16* G = BT + (size_t)(n0 + h * HW) * K + t * 64;
#pragma unroll
      for (int i = 0; i < LB0; ++i) {
        int id = i * 256 + tid, row = id >> 3, ch = id & 7;
        // h*HW multiple of 8 -> (local row & 7) == (global row & 7)
        ld16_lds(G + (size_t)row * K + (ch ^ (row & 7)) * 8, Bd + (h * HW * 64) + id * 8);
      }
    }
  };

  // ---- register fragments: single sets (no spill) ----
  bf16x8 af[4][2], b0[NH][2], b1[NH][2];
  auto ldAF = [&](const u16* Ab) {
#pragma unroll
    for (int i = 0; i < 4; ++i)
#pragma unroll
      for (int ks = 0; ks < 2; ++ks) {
        int r = wr * 64 + i * 16 + l16;
        af[i][ks] = *(const bf16x8*)&Ab[r * 64 + (((ks * 4 + quad) ^ (r & 7)) * 8)];
      }
  };
  auto ldB = [&](bf16x8 (&bv)[NH][2], int half, const u16* Bb) {
#pragma unroll
    for (int j = 0; j < NH; ++j)
#pragma unroll
      for (int ks = 0; ks < 2; ++ks) {
        int rb = half * HW + wc * SW + j * 16 + l16;
        bv[j][ks] = *(const bf16x8*)&Bb[rb * 64 + (((ks * 4 + quad) ^ (rb & 7)) * 8)];
      }
  };
  auto mmh = [&](const bf16x8 (&bv)[NH][2], int jo) {   // 4 x NH x 2 MFMA (T5 wrap)
    __builtin_amdgcn_s_setprio(1);
#pragma unroll
    for (int i = 0; i < 4; ++i)
#pragma unroll
      for (int j = 0; j < NH; ++j)
#pragma unroll
        for (int ks = 0; ks < 2; ++ks)
          acc[i][jo + j] =
              __builtin_amdgcn_mfma_f32_16x16x32_bf16(af[i][ks], bv[j][ks], acc[i][jo + j], 0, 0, 0);
    __builtin_amdgcn_s_setprio(0);
  };

  const int NT = K / 64;   // 32 for both GEMMs

  // ---- prologue: stage tiles 0 AND 1; drain tile0 (tile1's VMW stay flying) ----
  stage(0, As[0], Bs[0]);
  stage(1, As[1], Bs[1]);
  waitvm<VMW>();
  barrier();

#pragma unroll 2
  for (int t = 0; t < NT; ++t) {
    const int buf = t & 1;
    // issue all tile-t frag reads, group order pinned (b0, A, b1)
    ldB(b0, 0, Bs[buf]);
    __builtin_amdgcn_sched_barrier(0);
    ldAF(As[buf]);
    __builtin_amdgcn_sched_barrier(0);
    ldB(b1, 1, Bs[buf]);
    lgkmN<2 * NH>();          // b0 + A complete; b1 flying under mm0
    mmh(b0, 0);
    lgkmN<0>();               // b1 complete — buf fully read by this wave
    barrier();                // ...and by ALL waves: buf restage now safe
    if (t + 2 < NT) stage(t + 2, As[buf], Bs[buf]);   // ~1300cy cover to its wait
    mmh(b1, NH);
    if (t + 1 < NT) {
      if (t + 2 < NT) waitvm<VMW>();   // drain tile t+1 (issued last iter); t+2 flies
      else waitvm<0>();                // tail: nothing new staged
      barrier();                       // publish buf^1 for next iteration
    }
  }

  // ---- epilogue: C/D layout col=lane&15, row=quad*4+r ----
#pragma unroll
  for (int i = 0; i < 4; ++i) {
    int row = m0 + wr * 64 + i * 16 + quad * 4;
#pragma unroll
    for (int j = 0; j < NF; ++j) {
      int half = j / NH, jj = j % NH;
      int col = n0 + half * HW + wc * SW + jj * 16 + l16;
#pragma unroll
      for (int r = 0; r < 4; ++r) {
        size_t off = (size_t)(row + r) * N + col;
        if constexpr (sizeof(OutT) == 2) C[off] = f2bf(acc[i][j][r]);
        else C[off] = acc[i][j][r];
      }
    }
  }
}

// ---------------- kv_prep: RoPE K in-place + V tile images (Q handled in flash) --------
// Grid (8 kt, 8 kvh, 4 b) = 256 blocks. ~21MB traffic (K 8MB RMW + V 12MB + cs/sn)
// vs old rope_vkt's ~55MB (which also RMW'd all 32MB of Q).
__global__ __launch_bounds__(256) void kv_prep(u16* __restrict__ qkv,
                                               u16* __restrict__ vkt,
                                               const float* __restrict__ cs,
                                               const float* __restrict__ sn) {
  const int kt = blockIdx.x, kvh = blockIdx.y, b = blockIdx.z;
  const int tid = threadIdx.x;
  const size_t tok0 = (size_t)b * 1024 + (size_t)kt * 128;

  // ---- RoPE K: 2 threads per row, 2 pair-groups (8 pairs each) per thread ----
  {
    const int r = tid >> 1, hf = tid & 1;
    const size_t t = tok0 + r;
    const float* cr = cs + t * 32;
    const float* sr = sn + t * 32;
    u16* krow = qkv + t * 3072 + 2048 + kvh * 64;
#pragma unroll
    for (int gg = 0; gg < 2; ++gg) {
      const int g = hf * 2 + gg;                  // pair-group 0..3 (d = g*8+e)
      bf16x8 a = *(bf16x8*)&krow[g * 8];
      bf16x8 b2 = *(bf16x8*)&krow[g * 8 + 32];
#pragma unroll
      for (int e = 0; e < 8; ++e) {
        float cv = cr[g * 8 + e], sv = sr[g * 8 + e];
        float x1 = (float)a[e], x2 = (float)b2[e];
        a[e] = (__bf16)(x1 * cv - x2 * sv);
        b2[e] = (__bf16)(x2 * cv + x1 * sv);
      }
      *(bf16x8*)&krow[g * 8] = a;
      *(bf16x8*)&krow[g * 8 + 32] = b2;
    }
  }

  // ---- V image build (transposed, chunk-swizzled, k-permuted) ----
  __shared__ u16 Vn[128 * 64];
  const u16* src = qkv + tok0 * 3072 + 2560 + kvh * 64;
  {
    int tok = tid >> 1, hf = tid & 1;
    const uint4* s4 = (const uint4*)(src + (size_t)tok * 3072 + hf * 32);
    uint4* d4 = (uint4*)&Vn[tok * 64 + hf * 32];
#pragma unroll
    for (int j = 0; j < 4; j++) d4[j] = s4[j];
  }
  __syncthreads();
  u16* img = vkt + ((((size_t)b * 8 + kvh) * 8 + kt) << 13);   // 8192 u16 / image
#pragma unroll
  for (int i = 0; i < 4; i++) {
    int c = tid * 4 + i;                 // chunk index 0..1023
    int dd = c >> 4, chsw = c & 15;
    int ch = chsw ^ (dd & 15);
    u16 tmp[8];
#pragma unroll
    for (int p = 0; p < 8; p++) {
      int col = ch * 8 + p;
      int g = col >> 5, kl = col & 31;
      int kph = ((kl >> 2) & 1) * 16 + ((kl >> 4) & 1) * 8 + ((kl >> 3) & 1) * 4 + (kl & 3);
      tmp[p] = Vn[(g * 32 + kph) * 64 + dd];
    }
    *(uint4*)&img[c * 8] = *(const uint4*)tmp;
  }
}

// ---------------- flash attention v5: Q-rope fused in-block ----------------
// Grid (4, 32, 4) = 512 blocks = 2/CU. Two q-tiles per block (qtA=bx, qtB=7-bx):
// 9 tile-steps per block, K/V staged once for both. Transposed-score form,
// max-free exp2 softmax, P kept in registers via the k-permutation baked into
// the VkT images. K and VT double-buffered pure DMA. One barrier/iter.
// NEW: Q tiles are roped IN LDS right after staging (one RMW pass, outside the
// main loop). Pair (d,d+32) of row r lives at swizzled chunks g^(r&7) and
// (g+4)^(r&7) — same XOR, disjoint 16B chunks per thread, so the pass is
// race-free with one barrier each side. Numerics identical to the old pre-pass
// (bf16 in -> f32 rope -> bf16 out).
// LDS: Ks 2x16KB + VT 2x16KB = 64KB -> 2 blocks/CU. T5 setprio on MFMA clusters.
__global__ __launch_bounds__(256, 2) void flash_attn(const u16* __restrict__ qkv,
                                                     const u16* __restrict__ vkt,
                                                     u16* __restrict__ attn,
                                                     const float* __restrict__ cs,
                                                     const float* __restrict__ sn) {
  __shared__ u16 Ks[2][128 * 64];
  __shared__ u16 VT[2][64 * 128];

  const int tid = threadIdx.x;
  const int lane = tid & 63, wave = tid >> 6;
  const int quad = lane >> 4, l16 = lane & 15;
  const int qtA = blockIdx.x, qtB = 7 - blockIdx.x;
  const int h = blockIdx.y, b = blockIdx.z, kvh = h >> 2;
  const size_t tokBase = (size_t)b * 1024;
  const int qcol = h * 64, kcol = 2048 + kvh * 64;
  const int srow = tid >> 3, spc = tid & 7, ssc = spc ^ (srow & 7);

  auto stageK = [&](const u16* gbase, u16* L) {   // natural 128x64, swizzled chunks
#pragma unroll
    for (int i = 0; i < 4; i++)
      ld16_lds(gbase + (size_t)(srow + i * 32) * 3072 + ssc * 8, &L[tid * 8 + i * 2048]);
  };
  const u16* vimg = vkt + (((size_t)b * 8 + kvh) << 16);
  auto stageV = [&](int kt, u16* L) {             // pre-swizzled image: linear copy
    const u16* g = vimg + ((size_t)kt << 13);
#pragma unroll
    for (int i = 0; i < 4; i++)
      ld16_lds(g + i * 2048 + tid * 8, &L[tid * 8 + i * 2048]);
  };

  // ---- stage both Q tiles into the K buffers ----
  stageK(qkv + (tokBase + qtA * 128) * 3072 + qcol, Ks[0]);
  stageK(qkv + (tokBase + qtB * 128) * 3072 + qcol, Ks[1]);
  __syncthreads();

  // ---- RoPE both Q tiles in LDS (fused; was rope_vkt's Q pass) ----
  {
    const int r = tid >> 1, hf = tid & 1;        // row 0..127, group pair owner
#pragma unroll
    for (int qt = 0; qt < 2; ++qt) {
      u16* L = (qt == 0) ? Ks[0] : Ks[1];
      const size_t t = tokBase + (size_t)((qt == 0) ? qtA : qtB) * 128 + r;
      const float* cr = cs + t * 32;
      const float* sr = sn + t * 32;
#pragma unroll
      for (int gg = 0; gg < 2; ++gg) {
        const int g = hf * 2 + gg;               // global chunk g (d in [g*8,g*8+8))
        const int c1 = g ^ (r & 7);              // swizzled LDS chunk of d
        const int c2 = (g + 4) ^ (r & 7);        //   ... and of d+32
        bf16x8 a = *(bf16x8*)&L[r * 64 + c1 * 8];
        bf16x8 b2 = *(bf16x8*)&L[r * 64 + c2 * 8];
#pragma unroll
        for (int e = 0; e < 8; ++e) {
          float cv = cr[g * 8 + e], sv = sr[g * 8 + e];
          float x1 = (float)a[e], x2 = (float)b2[e];
          a[e] = (__bf16)(x1 * cv - x2 * sv);
          b2[e] = (__bf16)(x2 * cv + x1 * sv);
        }
        *(bf16x8*)&L[r * 64 + c1 * 8] = a;
        *(bf16x8*)&L[r * 64 + c2 * 8] = b2;
      }
    }
  }
  __syncthreads();

  // ---- extract Q fragments (roped) ----
  bf16x8 qfA[2][2], qfB[2][2];   // B-frag: n=q=l16, kdim=d contiguous
#pragma unroll
  for (int nq = 0; nq < 2; nq++) {
    int qrow = wave * 32 + nq * 16 + l16;
#pragma unroll
    for (int ks = 0; ks < 2; ks++) {
      int c = (ks * 4 + quad) ^ (qrow & 7);
      qfA[nq][ks] = *(const bf16x8*)&Ks[0][qrow * 64 + c * 8];
      qfB[nq][ks] = *(const bf16x8*)&Ks[1][qrow * 64 + c * 8];
    }
  }
  __syncthreads();   // Q reads done before K DMA overwrites

  float lA[2] = {0.f, 0.f}, lB[2] = {0.f, 0.f};
  f32x4 oA[4][2] = {}, oB[4][2] = {};   // O^T: d=md*16+quad*4+r, q=nq*16+l16

  auto proc = [&](const bf16x8 (&kf)[2][2], const bf16x8 (&va)[4], const bf16x8 (&qf)[2][2],
                  f32x4 (&o)[4][2], float (&lacc)[2], bool msk, int c) {
    f32x4 s[2][2] = {};   // [nq][mkl]: k = (c*2+mkl)*16 + quad*4 + r, q = nq*16+l16
    __builtin_amdgcn_s_setprio(1);
#pragma unroll
    for (int mkl = 0; mkl < 2; mkl++)
#pragma unroll
      for (int ks = 0; ks < 2; ks++) {
        s[0][mkl] = __builtin_amdgcn_mfma_f32_16x16x32_bf16(kf[mkl][ks], qf[0][ks], s[0][mkl], 0, 0, 0);
        s[1][mkl] = __builtin_amdgcn_mfma_f32_16x16x32_bf16(kf[mkl][ks], qf[1][ks], s[1][mkl], 0, 0, 0);
      }
    __builtin_amdgcn_s_setprio(0);
    if (msk) {
#pragma unroll
      for (int nq = 0; nq < 2; nq++) {
        int q = wave * 32 + nq * 16 + l16;
#pragma unroll
        for (int mkl = 0; mkl < 2; mkl++)
#pragma unroll
          for (int r = 0; r < 4; r++)
            if ((c * 2 + mkl) * 16 + quad * 4 + r > q) s[nq][mkl][r] = -3e38f;
      }
    }
    bf16x8 pf[2];
#pragma unroll
    for (int nq = 0; nq < 2; nq++) {
      float a0 = 0.f;
#pragma unroll
      for (int mkl = 0; mkl < 2; mkl++)
#pragma unroll
        for (int r = 0; r < 4; r++) {
          float p = __builtin_amdgcn_exp2f(s[nq][mkl][r]);
          s[nq][mkl][r] = p;
          a0 += p;
        }
      lacc[nq] += a0;
      pf[nq][0] = (__bf16)s[nq][0][0]; pf[nq][1] = (__bf16)s[nq][0][1];
      pf[nq][2] = (__bf16)s[nq][0][2]; pf[nq][3] = (__bf16)s[nq][0][3];
      pf[nq][4] = (__bf16)s[nq][1][0]; pf[nq][5] = (__bf16)s[nq][1][1];
      pf[nq][6] = (__bf16)s[nq][1][2]; pf[nq][7] = (__bf16)s[nq][1][3];
    }
    __builtin_amdgcn_s_setprio(1);
#pragma unroll
    for (int md = 0; md < 4; md++) {
      o[md][0] = __builtin_amdgcn_mfma_f32_16x16x32_bf16(va[md], pf[0], o[md][0], 0, 0, 0);
      o[md][1] = __builtin_amdgcn_mfma_f32_16x16x32_bf16(va[md], pf[1], o[md][1], 0, 0, 0);
    }
    __builtin_amdgcn_s_setprio(0);
  };

  // ---- main loop: double-buffered K + VT DMA, one barrier per iteration ----
  stageK(qkv + tokBase * 3072 + kcol, Ks[0]);
  stageV(0, VT[0]);

  for (int kt = 0; kt <= qtB; kt++) {
    const int cur = kt & 1;
    __syncthreads();   // drains DMA for kt; all waves done with bufs[1-cur]
    if (kt < qtB) {
      stageK(qkv + (tokBase + (kt + 1) * 128) * 3072 + kcol, Ks[1 - cur]);
      stageV(kt + 1, VT[1 - cur]);
    }
    const bool doA = (kt <= qtA), mA = (kt == qtA), mB = (kt == qtB);
    const u16* K = Ks[cur];
    const u16* V = VT[cur];
#pragma unroll
    for (int c = 0; c < 4; c++) {
      bf16x8 kf[2][2];   // A-frag: m=krow=mk*16+l16, kdim=d
#pragma unroll
      for (int mkl = 0; mkl < 2; mkl++) {
        int krow = (c * 2 + mkl) * 16 + l16;
#pragma unroll
        for (int ks = 0; ks < 2; ks++)
          kf[mkl][ks] = *(const bf16x8*)&K[krow * 64 + ((ks * 4 + quad) ^ (krow & 7)) * 8];
      }
      bf16x8 va[4];      // A-frag V^T: m=d=md*16+l16, k-chunk c
#pragma unroll
      for (int md = 0; md < 4; md++) {
        int dd = md * 16 + l16;
        va[md] = *(const bf16x8*)&V[dd * 128 + ((c * 4 + quad) ^ l16) * 8];
      }
      proc(kf, va, qfB, oB, lB, mB, c);
      if (doA) proc(kf, va, qfA, oA, lA, mA, c);
    }
  }

  // ---- epilogue: reduce l across quads (2 shfls), O/l, b64 stores ----
  auto epilogue = [&](const f32x4 (&o)[4][2], const float (&lacc)[2], int qt_tile) {
#pragma unroll
    for (int nq = 0; nq < 2; nq++) {
      float l = lacc[nq];
      l += __shfl_xor(l, 16);
      l += __shfl_xor(l, 32);
      float inv = 1.0f / l;
      int t = qt_tile * 128 + wave * 32 + nq * 16 + l16;
      size_t rowOff = (tokBase + t) * 2048 + qcol;
#pragma unroll
      for (int md = 0; md < 4; md++) {
        bf16x4 w;
        w[0] = (__bf16)(o[md][nq][0] * inv);
        w[1] = (__bf16)(o[md][nq][1] * inv);
        w[2] = (__bf16)(o[md][nq][2] * inv);
        w[3] = (__bf16)(o[md][nq][3] * inv);
        *(bf16x4*)&attn[rowOff + md * 16 + quad * 4] = w;
      }
    }
  };
  epilogue(oB, lB, qtB);
  epilogue(oA, lA, qtA);
}

// ---------------- launch ----------------
extern "C" void kernel_launch(void* const* d_in, const int* in_sizes, int n_in,
                              void* d_out, int out_size, void* d_ws, size_t ws_size,
                              hipStream_t stream) {
  const float* hs = (const float*)d_in[0];
  const float* cs = (const float*)d_in[1];
  const float* sn = (const float*)d_in[2];
  const float* Wq = (const float*)d_in[3];
  const float* Wk = (const float*)d_in[4];
  const float* Wv = (const float*)d_in[5];
  const float* Wo = (const float*)d_in[6];
  float* out = (float*)d_out;

  char* ws = (char*)d_ws;
  u16* hsB   = (u16*)(ws);                  // 4096x2048 bf16 (dead after qkv GEMM)
  u16* vkt   = (u16*)(ws);                  // 4MB VkT images, built after qkv GEMM
  u16* wqkvT = (u16*)(ws + 16777216);       // 3072x2048 bf16 [WqT;WkT;WvT]
  u16* woT   = (u16*)(ws + 29360128);       // 2048x2048 bf16
  u16* qkv   = (u16*)(ws + 37748736);       // 4096x3072 bf16
  u16* attnB = (u16*)(ws + 62914560);       // 4096x2048 bf16

  // attention scale folded into Wq: 1/8 * log2(e)  (rope commutes with the scale)
  const float QSCALE = 0.18033688011112042f;

  // fused prep: convert (8192 blocks) + Wq (4096) + Wk (1024) + Wv (1024) + Wo (4096)
  prep<<<18432, 256, 0, stream>>>(hs, hsB, Wq, Wk, Wv, Wo, wqkvT, woT, QSCALE);

  // QKV: 128x192 tile, 2-ahead counted-vmcnt pipeline, grid 16x32 = 512 = 2/CU.
  gemm6<u16, 192><<<dim3(16, 32), 256, 0, stream>>>(hsB, wqkvT, qkv, 4096, 3072, 2048);
  // RoPE K in-place + V images (Q roped inside flash).
  kv_prep<<<dim3(8, 8, 4), 256, 0, stream>>>(qkv, vkt, cs, sn);
  flash_attn<<<dim3(4, 32, 4), 256, 0, stream>>>(qkv, vkt, attnB, cs, sn);
  // Wo: 128x128 tile, grid 16x32 = 512 = 2/CU.
  gemm6<float, 128><<<dim3(16, 32), 256, 0, stream>>>(attnB, woT, out, 4096, 2048, 2048);
}